// Round 3
// baseline (206.835 us; speedup 1.0000x reference)
//
#include <hip/hip_runtime.h>
#include <hip/hip_bf16.h>

// Causal attention, S=4096, d=1024, fp32 in/out.
// bf16 MFMA for projections and PV; fp8 e4m3 MFMA (BK=128B) for scores only.
//
// Round-13 (this round): 8-phase 512-thread scores kernel (guide §5.5 T3+T4+T5
// full stack; m201 structure). 2-phase loops ceiling at ~600 TF (measured:
// k_sv 26.3GF/43.8us = 600 TF; counted-vmcnt alone was NULL, per regime-gate).
//   k_scores: BM=256 x BN=128 fp8 tiles, 8 waves (2Mx4N, wave tile 128x32),
//   dbuf 96KB LDS, 4 micro-phases per K-tile: {ds_read frag subtile || issue
//   stage of kt+1 -> s_barrier -> setprio(1) 16 MFMA setprio(0) -> s_barrier}.
//   Stage issues front-loaded (p0/p1) so boundary vmcnt(0) has 2-3 phases of
//   cover. 272 tri-grid blocks, 1 block/CU, 8 waves/CU.
//   Accumulation order bit-identical to round-12 -> absmax must be unchanged.
//   Vt merged into k_qkvv (768 blocks, validated 128^2 tile); k_sv removed.
//
// Workspace (256 MiB):
//   [0,8M)    x_bf  [4096,1024] bf16
//   [8M,12M)  Wqk   [2048,1024] bf16 (Wq rows 0..1023, Wk rows 1024..2047)
//   [12M,14M) Wv_bf [1024,1024] bf16
//   [14M,22M) QK    [4096,2048] fp8  (Q cols 0..1023, K cols 1024..2047)
//   [22M,30M) Vt    [1024,4096] bf16 (V^T, computed directly as Wv @ x^T)
//   [30M,62M) P~    [4096,4096] bf16 (exp(s/32), masked, unnormalized)
//   [62M,62.5M) rowsum_part [4096][32] fp32 (slot bn; dead slots zeroed)
//   [64M,100M) PV fp32 partials (72 multi-split groups x 8 bn x 64 KB)

typedef __bf16 bf16_t;
typedef __bf16 bf16x4v __attribute__((ext_vector_type(4)));
typedef __bf16 bf16x8 __attribute__((ext_vector_type(8)));
typedef float f32x4 __attribute__((ext_vector_type(4)));
typedef unsigned char u8;
typedef long long i64_t;

#define AS1 __attribute__((address_space(1)))
#define AS3 __attribute__((address_space(3)))
#define WAIT_VMCNT(N) asm volatile("s_waitcnt vmcnt(" #N ")" ::: "memory")
#define BARRIER_RAW() asm volatile("s_barrier" ::: "memory")

__device__ __forceinline__ void async_copy16(const void* g, void* l) {
    // 16B/lane direct global->LDS; LDS dest = wave-uniform base + lane*16
    __builtin_amdgcn_global_load_lds((AS1 void*)(g), (AS3 void*)(l), 16, 0, 0);
}

__device__ __forceinline__ u8 f32_to_fp8(float v) {
    // OCP e4m3 on gfx950 (HW conversion); layout validated in round 6
    return (u8)(__builtin_amdgcn_cvt_pk_fp8_f32(v, v, 0, false) & 0xff);
}

__device__ __forceinline__ void store_conv(float* p, float v) { *p = v; }
__device__ __forceinline__ void store_conv(bf16_t* p, float v) { *p = (bf16_t)v; }
__device__ __forceinline__ void store_conv(u8* p, float v) { *p = f32_to_fp8(v); }

// Sum of 32 consecutive floats (8x float4), for 1/rowsum computation.
__device__ __forceinline__ float sum32(const float* p) {
    const f32x4* v = (const f32x4*)p;
    float s = 0.f;
#pragma unroll
    for (int u = 0; u < 8; ++u) {
        f32x4 a = v[u];
        s += a[0] + a[1] + a[2] + a[3];
    }
    return s;
}

// ---------------- bf16 tile: BM=128, BN=128, BK=64 (validated r12) --------
// Double-buffered staging: A bufs [0,16K),[16K,32K); B bufs [32K,48K),[48K,64K).
// XOR-swizzled LDS (16B chunk b of row r holds k-chunk b^(r&7)).
// Counted-vmcnt 2-barrier K-loop. Epilogue: LDS-bounce -> 16B coalesced stores.
// EPI 0: C = v*alpha | EPI 2: C = v * inv[row] (inv indexed by tile-local row)
template <int EPI, typename OutT>
__device__ __forceinline__ void gemm_tile_bf16(const bf16_t* __restrict__ A, int lda,
                                               const bf16_t* __restrict__ B, int ldb,
                                               OutT* __restrict__ C, int ldc,
                                               int kb0, int kb1, float alpha,
                                               char* __restrict__ smem,
                                               const float* __restrict__ inv) {
    constexpr int BK = 64;
    bf16_t* As = (bf16_t*)smem;            // 2 x 8192 elems (16KB each)
    bf16_t* Bs = (bf16_t*)(smem + 32768);  // 2 x 8192 elems
    const int tid = threadIdx.x;
    const int lane = tid & 63, wave = tid >> 6;
    const int wm = wave >> 1, wn = wave & 1;
    const int q = lane >> 4, l16 = lane & 15;

    f32x4 acc[4][4] = {};

    const bf16_t* aSrc[4];
    const bf16_t* bSrc[4];
    int ldsOff[4];
#pragma unroll
    for (int it = 0; it < 4; ++it) {
        int c = it * 256 + tid;
        int r = c >> 3, b = c & 7;
        int sb = b ^ (r & 7);
        aSrc[it] = A + (size_t)r * lda + sb * 8;
        bSrc[it] = B + (size_t)r * ldb + sb * 8;
        ldsOff[it] = c * 8;
    }

    // prologue: stage first K-step into buffer 0 (8 loads in flight)
    {
        const int k0 = kb0 * BK;
#pragma unroll
        for (int it = 0; it < 4; ++it) async_copy16(aSrc[it] + k0, &As[ldsOff[it]]);
#pragma unroll
        for (int it = 0; it < 4; ++it) async_copy16(bSrc[it] + k0, &Bs[ldsOff[it]]);
    }

    int cur = 0;
    for (int kb = kb0; kb < kb1; ++kb) {
        if (kb + 1 < kb1) {  // prefetch next K-step into alternate buffer
            const int k0 = (kb + 1) * BK;
            const int boff = (cur ^ 1) * 8192;
#pragma unroll
            for (int it = 0; it < 4; ++it) async_copy16(aSrc[it] + k0, &As[boff + ldsOff[it]]);
#pragma unroll
            for (int it = 0; it < 4; ++it) async_copy16(bSrc[it] + k0, &Bs[boff + ldsOff[it]]);
            WAIT_VMCNT(8);   // tile-kb loads (8 oldest) retired; kb+1 in flight
        } else {
            WAIT_VMCNT(0);   // tail: drain everything
        }
        __builtin_amdgcn_sched_barrier(0);
        BARRIER_RAW();       // all waves' tile-kb loads landed
        const bf16_t* Ab = As + cur * 8192;
        const bf16_t* Bb = Bs + cur * 8192;
        __builtin_amdgcn_s_setprio(1);
#pragma unroll
        for (int k2 = 0; k2 < 2; ++k2) {
            bf16x8 af[4], bfr[4];
#pragma unroll
            for (int mt = 0; mt < 4; ++mt) {
                int m = wm * 64 + mt * 16 + l16;
                int blk = (k2 * 4 + q) ^ (m & 7);
                af[mt] = *(const bf16x8*)&Ab[m * BK + blk * 8];
            }
#pragma unroll
            for (int nt = 0; nt < 4; ++nt) {
                int nn = wn * 64 + nt * 16 + l16;
                int blk = (k2 * 4 + q) ^ (nn & 7);
                bfr[nt] = *(const bf16x8*)&Bb[nn * BK + blk * 8];
            }
#pragma unroll
            for (int mt = 0; mt < 4; ++mt)
#pragma unroll
                for (int nt = 0; nt < 4; ++nt)
                    acc[mt][nt] = __builtin_amdgcn_mfma_f32_16x16x32_bf16(
                        af[mt], bfr[nt], acc[mt][nt], 0, 0, 0);
        }
        __builtin_amdgcn_s_setprio(0);
        BARRIER_RAW();       // reads of buf done -> next iter may overwrite
        cur ^= 1;
    }

    // Epilogue: bounce C tile (128x128 OutT) through dead staging LDS.
    // C/D layout: col = lane&15, row = (lane>>4)*4 + reg.
    constexpr int S = (int)sizeof(OutT);
    constexpr int RB = 128 * S;  // bytes per tile row (128/256/512)
    const int row0 = wm * 64, col0 = wn * 64;
#pragma unroll
    for (int mt = 0; mt < 4; ++mt)
#pragma unroll
        for (int nt = 0; nt < 4; ++nt)
#pragma unroll
            for (int r = 0; r < 4; ++r) {
                int lr = row0 + mt * 16 + q * 4 + r;
                int lc = col0 + nt * 16 + l16;
                float v = acc[mt][nt][r];
                v = (EPI == 2) ? v * inv[lr] : v * alpha;
                int cb = (lc * S) >> 4;
                int sw = cb ^ ((lr >> 2) & 7);
                store_conv((OutT*)(smem + lr * RB + (sw << 4) + ((lc * S) & 15)), v);
            }
    __syncthreads();
    // stream out: 16B/thread/pass, fully coalesced (4 threads = one 64B line)
#pragma unroll
    for (int p = 0; p < 4 * S; ++p) {
        int g = p * 4096 + tid * 16;  // linear byte index in tile
        int r = g / RB;
        int wb = g & (RB - 1);
        int sc = (wb >> 4) ^ ((r >> 2) & 7);
        f32x4 val = *(const f32x4*)(smem + r * RB + (sc << 4));
        *(f32x4*)((char*)C + (size_t)r * ((size_t)ldc * S) + wb) = val;
    }
}

// ---------------- fp8 scores, 8-phase: BM=256, BN=128, BK=128B ------------
// 512 threads, 8 waves: wm=wave>>2 (M half), wn=wave&3 (32-col slice).
// Wave tile 128x32: M_rep=8, N_rep=2; acc 64 VGPR.
// LDS: buf0 A[0,32K) B[32K,48K); buf1 A[48K,80K) B[80K,96K); 96KB total.
// Per K-tile 4 phases (k2h x mh): 8-12 ds_read + 16 MFMA each, barriers
// around the MFMA cluster, setprio(1) inside. Stage of kt+1 issued at
// p0 (A0,A1,B0) and p1 (A2,A3,B1); boundary vmcnt(0) at p3 has >=2 phases
// of cover. Frag addressing identical to validated 128^2 fp8 tile.
__device__ __forceinline__ void read_afrags(i64_t af[4][2], const u8* Ab,
                                            int wm, int mh, int k2h,
                                            int l16, int q) {
#pragma unroll
    for (int mt = 0; mt < 4; ++mt)
#pragma unroll
        for (int kk = 0; kk < 2; ++kk) {
            int m = wm * 128 + (mh * 4 + mt) * 16 + l16;
            int k2 = k2h * 2 + kk;
            int cb = 2 * k2 + (q >> 1), co = (q & 1) * 8;
            af[mt][kk] = *(const i64_t*)&Ab[m * 128 + ((cb ^ (m & 7)) << 4) + co];
        }
}
__device__ __forceinline__ void read_bfrags(i64_t bf[2][2], const u8* Bb,
                                            int wn, int k2h, int l16, int q) {
#pragma unroll
    for (int nt = 0; nt < 2; ++nt)
#pragma unroll
        for (int kk = 0; kk < 2; ++kk) {
            int nn = wn * 32 + nt * 16 + l16;
            int k2 = k2h * 2 + kk;
            int cb = 2 * k2 + (q >> 1), co = (q & 1) * 8;
            bf[nt][kk] = *(const i64_t*)&Bb[nn * 128 + ((cb ^ (nn & 7)) << 4) + co];
        }
}

__global__ __launch_bounds__(512, 1) void k_scores(const u8* __restrict__ qk,
                                                   bf16_t* __restrict__ P,
                                                   float* __restrict__ rowsum_part) {
    __shared__ __attribute__((aligned(16))) char smem[98304];
    int t = blockIdx.x;  // 0..271, t = bm*(bm+1) + bn, bn in [0, 2bm+2)
    int bm = (int)(sqrtf((float)t + 0.25f) - 0.5f);
    while (bm * (bm + 1) > t) --bm;
    while ((bm + 1) * (bm + 2) <= t) ++bm;
    int bn = t - bm * (bm + 1);  // 0..2bm+1
    const u8* A = qk + (size_t)bm * 256 * 2048;          // Q rows (256)
    const u8* B = qk + 1024 + (size_t)bn * 128 * 2048;   // K rows (128)
    const int gr0 = bm * 256, gc0 = bn * 128;
    bf16_t* Cc = P + (size_t)bm * 256 * 4096 + bn * 128;
    float* partial = rowsum_part + (size_t)bm * 256 * 32 + bn;

    const int tid = threadIdx.x;
    const int lane = tid & 63, wave = tid >> 6;
    const int wm = wave >> 2, wn = wave & 3;
    const int q = lane >> 4, l16 = lane & 15;

    f32x4 acc[8][2] = {};

    // staging: A 4 passes (rows 0..255), B 2 passes (rows 0..127);
    // per pass 512 thr x 16B = 8KB. chunk g16=pp*512+tid; r=g16>>3; b=g16&7.
    const u8* aSrc[4]; int aOff[4];
    const u8* bSrc[2]; int bOff[2];
#pragma unroll
    for (int pp = 0; pp < 4; ++pp) {
        int g16 = pp * 512 + tid, r = g16 >> 3, b = g16 & 7, sb = b ^ (r & 7);
        aSrc[pp] = A + (size_t)r * 2048 + sb * 16;
        aOff[pp] = g16 * 16;
    }
#pragma unroll
    for (int pp = 0; pp < 2; ++pp) {
        int g16 = pp * 512 + tid, r = g16 >> 3, b = g16 & 7, sb = b ^ (r & 7);
        bSrc[pp] = B + (size_t)r * 2048 + sb * 16;
        bOff[pp] = g16 * 16;
    }

    // prologue: stage K-tile 0 into buf0
#pragma unroll
    for (int pp = 0; pp < 4; ++pp) async_copy16(aSrc[pp], smem + aOff[pp]);
#pragma unroll
    for (int pp = 0; pp < 2; ++pp) async_copy16(bSrc[pp], smem + 32768 + bOff[pp]);
    WAIT_VMCNT(0);
    BARRIER_RAW();

    for (int kt = 0; kt < 8; ++kt) {
        const char* bufb = smem + (kt & 1) * 49152;
        char* bufn = smem + ((kt & 1) ^ 1) * 49152;
        const u8* Ab = (const u8*)bufb;
        const u8* Bb = (const u8*)(bufb + 32768);
        const int k0n = (kt + 1) * 128;
        i64_t af[4][2], bf[2][2];

        // ---- p0: (k2h=0, mh=0); issue A0,A1,B0 of kt+1
        read_afrags(af, Ab, wm, 0, 0, l16, q);
        read_bfrags(bf, Bb, wn, 0, l16, q);
        if (kt < 7) {
            async_copy16(aSrc[0] + k0n, bufn + aOff[0]);
            async_copy16(aSrc[1] + k0n, bufn + aOff[1]);
            async_copy16(bSrc[0] + k0n, bufn + 32768 + bOff[0]);
        }
        BARRIER_RAW();
        __builtin_amdgcn_s_setprio(1);
#pragma unroll
        for (int mt = 0; mt < 4; ++mt)
#pragma unroll
            for (int nt = 0; nt < 2; ++nt)
#pragma unroll
                for (int kk = 0; kk < 2; ++kk)
                    acc[mt][nt] = __builtin_amdgcn_mfma_f32_16x16x32_fp8_fp8(
                        af[mt][kk], bf[nt][kk], acc[mt][nt], 0, 0, 0);
        __builtin_amdgcn_s_setprio(0);
        BARRIER_RAW();

        // ---- p1: (k2h=0, mh=1); issue A2,A3,B1 of kt+1
        read_afrags(af, Ab, wm, 1, 0, l16, q);
        if (kt < 7) {
            async_copy16(aSrc[2] + k0n, bufn + aOff[2]);
            async_copy16(aSrc[3] + k0n, bufn + aOff[3]);
            async_copy16(bSrc[1] + k0n, bufn + 32768 + bOff[1]);
        }
        BARRIER_RAW();
        __builtin_amdgcn_s_setprio(1);
#pragma unroll
        for (int mt = 0; mt < 4; ++mt)
#pragma unroll
            for (int nt = 0; nt < 2; ++nt)
#pragma unroll
                for (int kk = 0; kk < 2; ++kk)
                    acc[4 + mt][nt] = __builtin_amdgcn_mfma_f32_16x16x32_fp8_fp8(
                        af[mt][kk], bf[nt][kk], acc[4 + mt][nt], 0, 0, 0);
        __builtin_amdgcn_s_setprio(0);
        BARRIER_RAW();

        // ---- p2: (k2h=1, mh=0)
        read_afrags(af, Ab, wm, 0, 1, l16, q);
        read_bfrags(bf, Bb, wn, 1, l16, q);
        BARRIER_RAW();
        __builtin_amdgcn_s_setprio(1);
#pragma unroll
        for (int mt = 0; mt < 4; ++mt)
#pragma unroll
            for (int nt = 0; nt < 2; ++nt)
#pragma unroll
                for (int kk = 0; kk < 2; ++kk)
                    acc[mt][nt] = __builtin_amdgcn_mfma_f32_16x16x32_fp8_fp8(
                        af[mt][kk], bf[nt][kk], acc[mt][nt], 0, 0, 0);
        __builtin_amdgcn_s_setprio(0);
        BARRIER_RAW();

        // ---- p3: (k2h=1, mh=1); boundary wait
        read_afrags(af, Ab, wm, 1, 1, l16, q);
        BARRIER_RAW();
        __builtin_amdgcn_s_setprio(1);
#pragma unroll
        for (int mt = 0; mt < 4; ++mt)
#pragma unroll
            for (int nt = 0; nt < 2; ++nt)
#pragma unroll
                for (int kk = 0; kk < 2; ++kk)
                    acc[4 + mt][nt] = __builtin_amdgcn_mfma_f32_16x16x32_fp8_fp8(
                        af[mt][kk], bf[nt][kk], acc[4 + mt][nt], 0, 0, 0);
        __builtin_amdgcn_s_setprio(0);
        if (kt < 7) WAIT_VMCNT(0);  // kt+1 fully landed (issued >=2 phases ago)
        BARRIER_RAW();              // boundary: all waves ready for buf flip
    }

    // Epilogue: P = exp(v/32) masked -> LDS bounce (bf16 256x128, 64KB at
    // [0,64K)) + per-row sums (sred 256x4 f32 at +64K).
    float* sred = (float*)(smem + 65536);
    float esum[8][4];
#pragma unroll
    for (int mt = 0; mt < 8; ++mt)
#pragma unroll
        for (int r = 0; r < 4; ++r) esum[mt][r] = 0.f;
#pragma unroll
    for (int mt = 0; mt < 8; ++mt)
#pragma unroll
        for (int nt = 0; nt < 2; ++nt)
#pragma unroll
            for (int r = 0; r < 4; ++r) {
                int lr = wm * 128 + mt * 16 + q * 4 + r;
                int lc = wn * 32 + nt * 16 + l16;
                float pe = (gc0 + lc > gr0 + lr) ? 0.f
                                                 : __expf(acc[mt][nt][r] * 0.03125f);
                esum[mt][r] += pe;
                int sw = (lc >> 3) ^ ((lr >> 2) & 7);
                *(bf16_t*)(smem + lr * 256 + (sw << 4) + ((lc * 2) & 15)) = (bf16_t)pe;
            }
#pragma unroll
    for (int mt = 0; mt < 8; ++mt)
#pragma unroll
        for (int r = 0; r < 4; ++r) {
            float s = esum[mt][r];
#pragma unroll
            for (int off = 1; off < 16; off <<= 1)
                s += __shfl_xor(s, off, 64);
            if (l16 == 0)
                sred[(wm * 128 + mt * 16 + q * 4 + r) * 4 + wn] = s;
        }
    __syncthreads();
    // stream P tile out: 8 passes x 16B/thread, coalesced 256B rows
#pragma unroll
    for (int p = 0; p < 8; ++p) {
        int g = p * 8192 + tid * 16;
        int r = g >> 8, wb = g & 255;
        int sc = (wb >> 4) ^ ((r >> 2) & 7);
        f32x4 val = *(const f32x4*)(smem + r * 256 + (sc << 4));
        *(f32x4*)((char*)Cc + (size_t)r * 8192 + wb) = val;
    }
    if (tid < 256)
        partial[(size_t)tid * 32] =
            sred[tid * 4] + sred[tid * 4 + 1] + sred[tid * 4 + 2] + sred[tid * 4 + 3];
    if (bn == 2 * bm + 1) {  // rightmost tile: zero dead rowsum slots
        float* rp = rowsum_part + (size_t)bm * 256 * 32;
        for (int r = tid >> 4; r < 256; r += 32)
            for (int u = 2 * bm + 2 + (tid & 15); u < 32; u += 16)
                rp[r * 32 + u] = 0.f;
    }
}

// Merged projections: 768 blocks (2/CU), 16 bf16 kb-iters each.
//   b in [0,512):   QK = x @ [Wq;Wk]^T -> [4096,2048] fp8
//   b in [512,768): Vt = Wv @ x^T -> [1024,4096] bf16
__global__ __launch_bounds__(256) void k_qkvv(const bf16_t* __restrict__ xb,
                                              const bf16_t* __restrict__ wqk,
                                              const bf16_t* __restrict__ wvb,
                                              u8* __restrict__ qk,
                                              bf16_t* __restrict__ vt) {
    __shared__ __attribute__((aligned(16))) char smem[65536];
    int b = blockIdx.x;
    if (b < 512) {
        int bm = b & 31, bn = b >> 5;  // bn 0..15
        gemm_tile_bf16<0, u8>(xb + (size_t)bm * 128 * 1024, 1024,
                              wqk + (size_t)bn * 128 * 1024, 1024,
                              qk + (size_t)bm * 128 * 2048 + bn * 128, 2048,
                              0, 16, 1.f, smem, nullptr);
    } else {
        int bb = b - 512;
        int bm = bb & 7, bn = bb >> 3;  // bn 0..31
        gemm_tile_bf16<0, bf16_t>(wvb + (size_t)bm * 128 * 1024, 1024,
                                  xb + (size_t)bn * 128 * 1024, 1024,
                                  vt + (size_t)bm * 128 * 4096 + bn * 128, 4096,
                                  0, 16, 1.f, smem, nullptr);
    }
}

// O = (P~ @ V) * diag(1/rowsum), bf16, BK=64: nk = 2(bm+1) iters.
// Split-K chunk 16: 80 (bm,s) groups x 8 bn = 640 compact blocks.
// Single-split (bm<=7) computes 1/rowsum into LDS and stores direct;
// multi-split writes fp32 partials (16B coalesced via bounce) for k_reduce.
__global__ __launch_bounds__(256) void k_pv(const bf16_t* __restrict__ P,
                                            const bf16_t* __restrict__ vt,
                                            const float* __restrict__ rowsum_part,
                                            float* __restrict__ out,
                                            float* __restrict__ partials) {
    __shared__ __attribute__((aligned(16))) char smem[65536];
    __shared__ float sInv[128];
    int b = blockIdx.x;
    int bn = b & 7, g = b >> 3;
    int bm, s, ns;
    if (g < 8)       { bm = g;                 s = 0;            ns = 1; }
    else if (g < 24) { bm = 8 + (g - 8) / 2;   s = (g - 8) % 2;  ns = 2; }
    else if (g < 48) { bm = 16 + (g - 24) / 3; s = (g - 24) % 3; ns = 3; }
    else             { bm = 24 + (g - 48) / 4; s = (g - 48) % 4; ns = 4; }
    int nk = 2 * (bm + 1);
    int kb0 = s * nk / ns;
    int kb1 = (s + 1) * nk / ns;

    const bf16_t* A = P + (size_t)bm * 128 * 4096;
    const bf16_t* B = vt + (size_t)bn * 128 * 4096;
    if (ns == 1) {
        int tid = threadIdx.x;
        if (tid < 128)
            sInv[tid] = 1.f / sum32(rowsum_part + (size_t)(bm * 128 + tid) * 32);
        // visibility of sInv covered by the K-loop's first barrier
        gemm_tile_bf16<2, float>(A, 4096, B, 4096,
                                 out + (size_t)bm * 128 * 1024 + bn * 128, 1024,
                                 kb0, kb1, 1.f, smem, sInv);
    } else {
        int cum = (bm < 16) ? (bm - 8) * 2
                : (bm < 24) ? 16 + (bm - 16) * 3
                            : 40 + (bm - 24) * 4;
        gemm_tile_bf16<0, float>(A, 4096, B, 4096,
                                 partials + ((size_t)(cum + s) * 8 + bn) * 16384, 128,
                                 kb0, kb1, 1.f, smem, nullptr);
    }
}

// out tiles for bm in [8,31]: sum 2..4 fp32 partials, scale by 1/rowsum.
// Compact 3072 blocks: t = b%192 -> (bm-8, bn); p = b/192 -> tile 16th
// (8 rows x 128 cols per block); float4/thread.
__global__ __launch_bounds__(256) void k_reduce(const float* __restrict__ partials,
                                                const float* __restrict__ rowsum_part,
                                                float* __restrict__ out) {
    int b = blockIdx.x;
    int t = b % 192, p = b / 192;
    int bm = t % 24 + 8, bn = t / 24;
    int ns = (bm < 16) ? 2 : (bm < 24) ? 3 : 4;
    int cum = (bm < 16) ? (bm - 8) * 2
            : (bm < 24) ? 16 + (bm - 16) * 3
                        : 40 + (bm - 24) * 4;
    __shared__ float sInv[8];
    int tid = threadIdx.x;
    if (tid < 8) {
        int row = bm * 128 + p * 8 + tid;
        sInv[tid] = 1.f / sum32(rowsum_part + (size_t)row * 32);
    }
    __syncthreads();

    int idx = p * 1024 + tid * 4;
    int lr = idx >> 7, lc = idx & 127;
    float sx = 0.f, sy = 0.f, sz = 0.f, sw = 0.f;
    for (int u = 0; u < ns; ++u) {
        const float4 v = *(const float4*)(partials + ((size_t)(cum + u) * 8 + bn) * 16384 + idx);
        sx += v.x; sy += v.y; sz += v.z; sw += v.w;
    }
    float inv = sInv[lr - p * 8];
    float4 o = {sx * inv, sy * inv, sz * inv, sw * inv};
    *(float4*)(out + (size_t)(bm * 128 + lr) * 1024 + bn * 128 + lc) = o;
}

// fp32 -> bf16 casts: x -> x_bf, Wq|Wk -> Wqk (concat), Wv -> Wv_bf.
__global__ __launch_bounds__(256) void cast_to_bf16(const float* __restrict__ x,
                                                    const float* __restrict__ Wq,
                                                    const float* __restrict__ Wk,
                                                    const float* __restrict__ Wv,
                                                    bf16_t* __restrict__ xb,
                                                    bf16_t* __restrict__ wqk,
                                                    bf16_t* __restrict__ wv) {
    const int NX = (4096 * 1024) / 4;
    const int NW = (1024 * 1024) / 4;
    int idx = blockIdx.x * 256 + threadIdx.x;
    const float* src;
    bf16_t* dst;
    int off;
    if (idx < NX) {
        src = x; dst = xb; off = idx;
    } else if (idx < NX + NW) {
        src = Wq; dst = wqk; off = idx - NX;
    } else if (idx < NX + 2 * NW) {
        src = Wk; dst = wqk + (size_t)NW * 4; off = idx - NX - NW;
    } else {
        src = Wv; dst = wv; off = idx - NX - 2 * NW;
    }
    float4 f = ((const float4*)src)[off];
    bf16x4v o;
    o.x = (bf16_t)f.x; o.y = (bf16_t)f.y; o.z = (bf16_t)f.z; o.w = (bf16_t)f.w;
    *(bf16x4v*)(dst + (size_t)off * 4) = o;
}

extern "C" void kernel_launch(void* const* d_in, const int* in_sizes, int n_in,
                              void* d_out, int out_size, void* d_ws, size_t ws_size,
                              hipStream_t stream) {
    (void)in_sizes; (void)n_in; (void)out_size; (void)ws_size;
    const float* x  = (const float*)d_in[0];
    const float* Wq = (const float*)d_in[1];
    const float* Wk = (const float*)d_in[2];
    const float* Wv = (const float*)d_in[3];
    float* out = (float*)d_out;

    char* ws = (char*)d_ws;
    bf16_t* xb   = (bf16_t*)(ws + (size_t)0);
    bf16_t* wqk  = (bf16_t*)(ws + ((size_t)8 << 20));
    bf16_t* wvb  = (bf16_t*)(ws + ((size_t)12 << 20));
    u8*     qk   = (u8*)(ws + ((size_t)14 << 20));
    bf16_t* vt   = (bf16_t*)(ws + ((size_t)22 << 20));
    bf16_t* P    = (bf16_t*)(ws + ((size_t)30 << 20));
    float* rowsp = (float*)(ws + ((size_t)62 << 20));
    float* parts = (float*)(ws + ((size_t)64 << 20));

    cast_to_bf16<<<7168, 256, 0, stream>>>(x, Wq, Wk, Wv, xb, wqk, wvb);

    // QK (fp8) = x@[Wq;Wk]^T + Vt (bf16) = Wv@x^T (768 blocks, 2/CU)
    k_qkvv<<<768, 256, 0, stream>>>(xb, wqk, wvb, qk, vt);

    // P~ = exp((Q@K^T)/32) causal, 256x128 fp8 8-phase tiles (272 blocks)
    k_scores<<<272, 512, 0, stream>>>(qk, P, rowsp);

    // out = (P~ @ V) * diag(1/rowsum): split-K chunk 16 + partial reduction
    k_pv<<<640, 256, 0, stream>>>(P, vt, rowsp, out, parts);
    k_reduce<<<3072, 256, 0, stream>>>(parts, rowsp, out);
}

// Round 5
// 186.593 us; speedup vs baseline: 1.1085x; 1.1085x over previous
//
#include <hip/hip_runtime.h>
#include <hip/hip_bf16.h>

// Causal attention, S=4096, d=1024, fp32 in/out.
// bf16 MFMA for projections and PV; fp8 e4m3 MFMA for scores only.
//
// Round-15: RESUBMIT of round-14 (container failed twice before the bench
// ran; no counters, no pass/fail). Static re-audit found no hazard: uniform
// barrier counts (4/iter x 16 + prologue), exact per-wave vmcnt ledger
// (12 outstanding -> vmcnt(8) retires half h+1 each iter; tails 8/4/0),
// WAR on ring slot (h+3)&3 covered by iteration h-1's trailing barrier,
// staging addresses in bounds. Attributing the failure to infra; one retry.
//
// Round-14: deep-pipelined scores tile inside the proven r12 shell.
//   - K split into 16 half-tiles (64B); ring of 4 half-buffers (64KB LDS)
//   - 3 halves (12 loads) in flight; counted vmcnt(8) per half boundary
//     (never 0 in steady loop); tails 8/4/0 derived
//   - per half 2 phases {ds_read || 2 stage issues -> bar -> lgkm0 ->
//     setprio(1) 16 MFMA setprio(0) -> bar}
//   - 64B rows, chunk swz c^((r>>1)&3) -> 2-way bank aliasing (free, m136)
//   - accumulation order bit-identical to r12 -> absmax canary 0.02734375
//
// Workspace (256 MiB):
//   [0,8M)    x_bf  [4096,1024] bf16
//   [8M,12M)  Wqk   [2048,1024] bf16 (Wq rows 0..1023, Wk rows 1024..2047)
//   [12M,14M) Wv_bf [1024,1024] bf16
//   [14M,22M) QK    [4096,2048] fp8  (Q cols 0..1023, K cols 1024..2047)
//   [22M,30M) Vt    [1024,4096] bf16 (V^T, computed directly as Wv @ x^T)
//   [30M,62M) P~    [4096,4096] bf16 (exp(s/32), masked, unnormalized)
//   [62M,62.5M) rowsum_part [4096][32] fp32 (slot bn; dead slots zeroed)
//   [64M,100M) PV fp32 partials (72 multi-split groups x 8 bn x 64 KB)

typedef __bf16 bf16_t;
typedef __bf16 bf16x4v __attribute__((ext_vector_type(4)));
typedef __bf16 bf16x8 __attribute__((ext_vector_type(8)));
typedef float f32x4 __attribute__((ext_vector_type(4)));
typedef unsigned char u8;
typedef long long i64_t;

#define AS1 __attribute__((address_space(1)))
#define AS3 __attribute__((address_space(3)))
#define WAIT_VMCNT(N) asm volatile("s_waitcnt vmcnt(" #N ")" ::: "memory")
#define WAIT_LGKM0() asm volatile("s_waitcnt lgkmcnt(0)" ::: "memory")
#define BARRIER_RAW() asm volatile("s_barrier" ::: "memory")

__device__ __forceinline__ void async_copy16(const void* g, void* l) {
    // 16B/lane direct global->LDS; LDS dest = wave-uniform base + lane*16
    __builtin_amdgcn_global_load_lds((AS1 void*)(g), (AS3 void*)(l), 16, 0, 0);
}

__device__ __forceinline__ u8 f32_to_fp8(float v) {
    // OCP e4m3 on gfx950 (HW conversion); layout validated in round 6
    return (u8)(__builtin_amdgcn_cvt_pk_fp8_f32(v, v, 0, false) & 0xff);
}

__device__ __forceinline__ void store_conv(float* p, float v) { *p = v; }
__device__ __forceinline__ void store_conv(bf16_t* p, float v) { *p = (bf16_t)v; }
__device__ __forceinline__ void store_conv(u8* p, float v) { *p = f32_to_fp8(v); }

// Sum of 32 consecutive floats (8x float4), for 1/rowsum computation.
__device__ __forceinline__ float sum32(const float* p) {
    const f32x4* v = (const f32x4*)p;
    float s = 0.f;
#pragma unroll
    for (int u = 0; u < 8; ++u) {
        f32x4 a = v[u];
        s += a[0] + a[1] + a[2] + a[3];
    }
    return s;
}

// ---------------- bf16 tile: BM=128, BN=128, BK=64 (validated r12) --------
// Double-buffered staging: A bufs [0,16K),[16K,32K); B bufs [32K,48K),[48K,64K).
// XOR-swizzled LDS (16B chunk b of row r holds k-chunk b^(r&7)).
// Counted-vmcnt 2-barrier K-loop. Epilogue: LDS-bounce -> 16B coalesced stores.
// EPI 0: C = v*alpha | EPI 2: C = v * inv[row] (inv indexed by tile-local row)
template <int EPI, typename OutT>
__device__ __forceinline__ void gemm_tile_bf16(const bf16_t* __restrict__ A, int lda,
                                               const bf16_t* __restrict__ B, int ldb,
                                               OutT* __restrict__ C, int ldc,
                                               int kb0, int kb1, float alpha,
                                               char* __restrict__ smem,
                                               const float* __restrict__ inv) {
    constexpr int BK = 64;
    bf16_t* As = (bf16_t*)smem;            // 2 x 8192 elems (16KB each)
    bf16_t* Bs = (bf16_t*)(smem + 32768);  // 2 x 8192 elems
    const int tid = threadIdx.x;
    const int lane = tid & 63, wave = tid >> 6;
    const int wm = wave >> 1, wn = wave & 1;
    const int q = lane >> 4, l16 = lane & 15;

    f32x4 acc[4][4] = {};

    const bf16_t* aSrc[4];
    const bf16_t* bSrc[4];
    int ldsOff[4];
#pragma unroll
    for (int it = 0; it < 4; ++it) {
        int c = it * 256 + tid;
        int r = c >> 3, b = c & 7;
        int sb = b ^ (r & 7);
        aSrc[it] = A + (size_t)r * lda + sb * 8;
        bSrc[it] = B + (size_t)r * ldb + sb * 8;
        ldsOff[it] = c * 8;
    }

    // prologue: stage first K-step into buffer 0 (8 loads in flight)
    {
        const int k0 = kb0 * BK;
#pragma unroll
        for (int it = 0; it < 4; ++it) async_copy16(aSrc[it] + k0, &As[ldsOff[it]]);
#pragma unroll
        for (int it = 0; it < 4; ++it) async_copy16(bSrc[it] + k0, &Bs[ldsOff[it]]);
    }

    int cur = 0;
    for (int kb = kb0; kb < kb1; ++kb) {
        if (kb + 1 < kb1) {  // prefetch next K-step into alternate buffer
            const int k0 = (kb + 1) * BK;
            const int boff = (cur ^ 1) * 8192;
#pragma unroll
            for (int it = 0; it < 4; ++it) async_copy16(aSrc[it] + k0, &As[boff + ldsOff[it]]);
#pragma unroll
            for (int it = 0; it < 4; ++it) async_copy16(bSrc[it] + k0, &Bs[boff + ldsOff[it]]);
            WAIT_VMCNT(8);   // tile-kb loads (8 oldest) retired; kb+1 in flight
        } else {
            WAIT_VMCNT(0);   // tail: drain everything
        }
        __builtin_amdgcn_sched_barrier(0);
        BARRIER_RAW();       // all waves' tile-kb loads landed
        const bf16_t* Ab = As + cur * 8192;
        const bf16_t* Bb = Bs + cur * 8192;
        __builtin_amdgcn_s_setprio(1);
#pragma unroll
        for (int k2 = 0; k2 < 2; ++k2) {
            bf16x8 af[4], bfr[4];
#pragma unroll
            for (int mt = 0; mt < 4; ++mt) {
                int m = wm * 64 + mt * 16 + l16;
                int blk = (k2 * 4 + q) ^ (m & 7);
                af[mt] = *(const bf16x8*)&Ab[m * BK + blk * 8];
            }
#pragma unroll
            for (int nt = 0; nt < 4; ++nt) {
                int nn = wn * 64 + nt * 16 + l16;
                int blk = (k2 * 4 + q) ^ (nn & 7);
                bfr[nt] = *(const bf16x8*)&Bb[nn * BK + blk * 8];
            }
#pragma unroll
            for (int mt = 0; mt < 4; ++mt)
#pragma unroll
                for (int nt = 0; nt < 4; ++nt)
                    acc[mt][nt] = __builtin_amdgcn_mfma_f32_16x16x32_bf16(
                        af[mt], bfr[nt], acc[mt][nt], 0, 0, 0);
        }
        __builtin_amdgcn_s_setprio(0);
        BARRIER_RAW();       // reads of buf done -> next iter may overwrite
        cur ^= 1;
    }

    // Epilogue: bounce C tile (128x128 OutT) through dead staging LDS.
    // C/D layout: col = lane&15, row = (lane>>4)*4 + reg.
    constexpr int S = (int)sizeof(OutT);
    constexpr int RB = 128 * S;  // bytes per tile row (128/256/512)
    const int row0 = wm * 64, col0 = wn * 64;
#pragma unroll
    for (int mt = 0; mt < 4; ++mt)
#pragma unroll
        for (int nt = 0; nt < 4; ++nt)
#pragma unroll
            for (int r = 0; r < 4; ++r) {
                int lr = row0 + mt * 16 + q * 4 + r;
                int lc = col0 + nt * 16 + l16;
                float v = acc[mt][nt][r];
                v = (EPI == 2) ? v * inv[lr] : v * alpha;
                int cb = (lc * S) >> 4;
                int sw = cb ^ ((lr >> 2) & 7);
                store_conv((OutT*)(smem + lr * RB + (sw << 4) + ((lc * S) & 15)), v);
            }
    __syncthreads();
    // stream out: 16B/thread/pass, fully coalesced (4 threads = one 64B line)
#pragma unroll
    for (int p = 0; p < 4 * S; ++p) {
        int g = p * 4096 + tid * 16;  // linear byte index in tile
        int r = g / RB;
        int wb = g & (RB - 1);
        int sc = (wb >> 4) ^ ((r >> 2) & 7);
        f32x4 val = *(const f32x4*)(smem + r * RB + (sc << 4));
        *(f32x4*)((char*)C + (size_t)r * ((size_t)ldc * S) + wb) = val;
    }
}

// ---------------- fp8 scores tile, deep-pipelined: 128x128 ----------------
// K = 1024B split into 16 half-tiles of 64B. Ring of 4 half-buffers, 16KB
// each (A[128x64] at +0, B[128x64] at +8192), 64KB total. Steady state: 3
// halves (12 loads) in flight; boundary wait = counted vmcnt(8) (m201/T4,
// never 0 in the main loop); tails vmcnt(4)@h13, vmcnt(0)@h14.
// Per half 2 phases: pA {ds_read B(8)+A01(4) || stage A(h+3)x2} -> bar ->
// lgkm0 -> setprio(1) 16 MFMA setprio(0) -> bar; pB {ds_read A23(4) ||
// stage B(h+3)x2} -> bar -> lgkm0 -> 16 MFMA -> vmcnt(N) -> bar.
// 64B LDS rows, chunk c of row r at slot c^((r>>1)&3) -> 2-way bank
// aliasing (free, m136). Global source pre-swizzled; LDS dest linear.
// Per-element accumulation order = r12 (k2 ascending 0..3) -> absmax canary.
// Epilogue: P = bf16(exp(v*alpha)) causally masked, LDS bounce -> 16B
// coalesced stores; per-row partial sums into `partial` (stride 32 floats).
__device__ __forceinline__ void scores_tile_fp8(const u8* __restrict__ A, int lda,
                                                const u8* __restrict__ B, int ldb,
                                                bf16_t* __restrict__ C, int ldc,
                                                float alpha, char* __restrict__ smem,
                                                float* __restrict__ partial,
                                                int gr0, int gc0) {
    const int tid = threadIdx.x;
    const int lane = tid & 63, wave = tid >> 6;
    const int wm = wave >> 1, wn = wave & 1;
    const int q = lane >> 4, l16 = lane & 15;

    f32x4 acc[4][4] = {};

    // staging sources, pre-swizzled; pass p covers rows p*64..p*64+63 (4KB)
    const u8* aS[2];
    const u8* bS[2];
    int lOff[2];
#pragma unroll
    for (int p = 0; p < 2; ++p) {
        int g = p * 256 + tid, r = g >> 2, c = g & 3;
        int sc = c ^ ((r >> 1) & 3);
        aS[p] = A + (size_t)r * lda + sc * 16;
        bS[p] = B + (size_t)r * ldb + sc * 16;
        lOff[p] = g * 16;
    }

    // prologue: stage halves 0,1,2 (12 loads; 4 per half)
#pragma unroll
    for (int h = 0; h < 3; ++h) {
        char* s = smem + h * 16384;
        async_copy16(aS[0] + h * 64, s + lOff[0]);
        async_copy16(aS[1] + h * 64, s + lOff[1]);
        async_copy16(bS[0] + h * 64, s + 8192 + lOff[0]);
        async_copy16(bS[1] + h * 64, s + 8192 + lOff[1]);
    }
    WAIT_VMCNT(8);  // halves 1,2 still in flight; half 0 landed
    __builtin_amdgcn_sched_barrier(0);
    BARRIER_RAW();

    for (int h = 0; h < 16; ++h) {
        const u8* Ab = (const u8*)(smem + (h & 3) * 16384);
        const u8* Bb = Ab + 8192;
        char* nslot = smem + ((h + 3) & 3) * 16384;
        const int kn = (h + 3) * 64;
        i64_t bf[4][2], af[2][2], af2[2][2];

        // ---- pA: B all-frags (8) + A rows 0..31 (4); stage A(h+3)
#pragma unroll
        for (int nt = 0; nt < 4; ++nt)
#pragma unroll
            for (int kk = 0; kk < 2; ++kk) {
                int nn = wn * 64 + nt * 16 + l16;
                int cb = kk * 2 + (q >> 1);
                bf[nt][kk] = *(const i64_t*)&Bb[nn * 64 + ((cb ^ ((nn >> 1) & 3)) << 4) + (q & 1) * 8];
            }
#pragma unroll
        for (int mt = 0; mt < 2; ++mt)
#pragma unroll
            for (int kk = 0; kk < 2; ++kk) {
                int m = wm * 64 + mt * 16 + l16;
                int cb = kk * 2 + (q >> 1);
                af[mt][kk] = *(const i64_t*)&Ab[m * 64 + ((cb ^ ((m >> 1) & 3)) << 4) + (q & 1) * 8];
            }
        if (h <= 12) {
            async_copy16(aS[0] + kn, nslot + lOff[0]);
            async_copy16(aS[1] + kn, nslot + lOff[1]);
        }
        BARRIER_RAW();
        WAIT_LGKM0();
        __builtin_amdgcn_sched_barrier(0);
        __builtin_amdgcn_s_setprio(1);
#pragma unroll
        for (int mt = 0; mt < 2; ++mt)
#pragma unroll
            for (int nt = 0; nt < 4; ++nt)
#pragma unroll
                for (int kk = 0; kk < 2; ++kk)
                    acc[mt][nt] = __builtin_amdgcn_mfma_f32_16x16x32_fp8_fp8(
                        af[mt][kk], bf[nt][kk], acc[mt][nt], 0, 0, 0);
        __builtin_amdgcn_s_setprio(0);
        BARRIER_RAW();

        // ---- pB: A rows 32..63 (4); stage B(h+3); derived boundary wait
#pragma unroll
        for (int mt = 0; mt < 2; ++mt)
#pragma unroll
            for (int kk = 0; kk < 2; ++kk) {
                int m = wm * 64 + (2 + mt) * 16 + l16;
                int cb = kk * 2 + (q >> 1);
                af2[mt][kk] = *(const i64_t*)&Ab[m * 64 + ((cb ^ ((m >> 1) & 3)) << 4) + (q & 1) * 8];
            }
        if (h <= 12) {
            async_copy16(bS[0] + kn, nslot + 8192 + lOff[0]);
            async_copy16(bS[1] + kn, nslot + 8192 + lOff[1]);
        }
        BARRIER_RAW();
        WAIT_LGKM0();
        __builtin_amdgcn_sched_barrier(0);
        __builtin_amdgcn_s_setprio(1);
#pragma unroll
        for (int mt = 0; mt < 2; ++mt)
#pragma unroll
            for (int nt = 0; nt < 4; ++nt)
#pragma unroll
                for (int kk = 0; kk < 2; ++kk)
                    acc[2 + mt][nt] = __builtin_amdgcn_mfma_f32_16x16x32_fp8_fp8(
                        af2[mt][kk], bf[nt][kk], acc[2 + mt][nt], 0, 0, 0);
        __builtin_amdgcn_s_setprio(0);
        // boundary: halves h+2,h+3 may stay in flight; h+1 must be landed
        if (h <= 12)      { WAIT_VMCNT(8); }
        else if (h == 13) { WAIT_VMCNT(4); }
        else if (h == 14) { WAIT_VMCNT(0); }
        __builtin_amdgcn_sched_barrier(0);
        BARRIER_RAW();
    }

    // Epilogue: P = exp(v*alpha) masked -> LDS bounce (bf16, 32KB) + per-row
    // sums via 16-lane shfl into sred (smem+32K, disjoint from bounce).
    float* sred = (float*)(smem + 32768);
    const int row0 = wm * 64, col0 = wn * 64;
    float esum[4][4];
#pragma unroll
    for (int mt = 0; mt < 4; ++mt)
#pragma unroll
        for (int r = 0; r < 4; ++r) esum[mt][r] = 0.f;
#pragma unroll
    for (int mt = 0; mt < 4; ++mt)
#pragma unroll
        for (int nt = 0; nt < 4; ++nt)
#pragma unroll
            for (int r = 0; r < 4; ++r) {
                int lr = row0 + mt * 16 + q * 4 + r;
                int lc = col0 + nt * 16 + l16;
                float pe = (gc0 + lc > gr0 + lr) ? 0.f : __expf(acc[mt][nt][r] * alpha);
                esum[mt][r] += pe;
                int sw = (lc >> 3) ^ ((lr >> 2) & 7);
                *(bf16_t*)(smem + lr * 256 + (sw << 4) + ((lc * 2) & 15)) = (bf16_t)pe;
            }
#pragma unroll
    for (int mt = 0; mt < 4; ++mt)
#pragma unroll
        for (int r = 0; r < 4; ++r) {
#pragma unroll
            for (int off = 1; off < 16; off <<= 1)
                esum[mt][r] += __shfl_xor(esum[mt][r], off, 64);
            if (l16 == 0) sred[(row0 + mt * 16 + q * 4 + r) * 2 + wn] = esum[mt][r];
        }
    __syncthreads();
    // stream P tile out: 8 passes x 16B/thread, coalesced 256B rows
#pragma unroll
    for (int p = 0; p < 8; ++p) {
        int g = p * 4096 + tid * 16;
        int r = g >> 8;
        int wb = g & 255;
        int sc = (wb >> 4) ^ ((r >> 2) & 7);
        f32x4 val = *(const f32x4*)(smem + r * 256 + (sc << 4));
        *(f32x4*)((char*)C + (size_t)r * ((size_t)ldc * 2) + wb) = val;
    }
    if (tid < 128) partial[(size_t)tid * 32] = sred[tid * 2] + sred[tid * 2 + 1];
}

// QK projection only: 512 uniform blocks (2/CU), 16 bf16 kb-iters each.
// QK = x @ [Wq;Wk]^T -> [4096,2048] fp8.
__global__ __launch_bounds__(256) void k_qkv(const bf16_t* __restrict__ xb,
                                             const bf16_t* __restrict__ wqk,
                                             u8* __restrict__ qk) {
    __shared__ __attribute__((aligned(16))) char smem[65536];
    int b = blockIdx.x;
    int bm = b & 31, bn = b >> 5;  // bn 0..15
    gemm_tile_bf16<0, u8>(xb + (size_t)bm * 128 * 1024, 1024,
                          wqk + (size_t)bn * 128 * 1024, 1024,
                          qk + (size_t)bm * 128 * 2048 + bn * 128, 2048,
                          0, 16, 1.f, smem, nullptr);
}

// Merged dispatch, 784 blocks (2/CU resident):
//   b in [0,256):   Vt = Wv @ x^T [1024,4096] bf16 (16 bf16 iters)
//   b in [256,784): P~ = exp((Q@K^T)/32) causal 128x128 tiles, fp8 deep
//     pipeline; compact tri grid t = bm(bm+1)/2 + bn (528 tiles); emits
//     per-row partial sums; diagonal tiles zero dead slots [bm+1,32).
__global__ __launch_bounds__(256) void k_sv(const bf16_t* __restrict__ xb,
                                            const bf16_t* __restrict__ wvb,
                                            const u8* __restrict__ qk,
                                            bf16_t* __restrict__ vt,
                                            bf16_t* __restrict__ P,
                                            float* __restrict__ rowsum_part) {
    __shared__ __attribute__((aligned(16))) char smem[65536];
    int b = blockIdx.x;
    if (b < 256) {
        int bm = b & 7, bn = b >> 3;  // bn 0..31
        gemm_tile_bf16<0, bf16_t>(wvb + (size_t)bm * 128 * 1024, 1024,
                                  xb + (size_t)bn * 128 * 1024, 1024,
                                  vt + (size_t)bm * 128 * 4096 + bn * 128, 4096,
                                  0, 16, 1.f, smem, nullptr);
        return;
    }
    int t = b - 256;  // 0..527
    int bm = (int)((sqrtf(8.f * (float)t + 1.f) - 1.f) * 0.5f);
    while (bm * (bm + 1) / 2 > t) --bm;
    while ((bm + 1) * (bm + 2) / 2 <= t) ++bm;
    int bn = t - bm * (bm + 1) / 2;  // 0..bm
    scores_tile_fp8(qk + (size_t)bm * 128 * 2048, 2048,
                    qk + 1024 + (size_t)bn * 128 * 2048, 2048,
                    P + (size_t)bm * 128 * 4096 + bn * 128, 4096,
                    0.03125f, smem,
                    rowsum_part + (size_t)bm * 128 * 32 + bn,
                    bm * 128, bn * 128);
    if (bn == bm) {  // zero dead rowsum slots for this row block
        float* rp = rowsum_part + (size_t)bm * 128 * 32;
        int tid = threadIdx.x;
        for (int r = tid >> 4; r < 128; r += 16)
            for (int u = bm + 1 + (tid & 15); u < 32; u += 16)
                rp[r * 32 + u] = 0.f;
    }
}

// O = (P~ @ V) * diag(1/rowsum), bf16, BK=64: nk = 2(bm+1) iters.
// Split-K chunk 16: 80 (bm,s) groups x 8 bn = 640 compact blocks.
// Single-split (bm<=7) computes 1/rowsum into LDS and stores direct;
// multi-split writes fp32 partials (16B coalesced via bounce) for k_reduce.
__global__ __launch_bounds__(256) void k_pv(const bf16_t* __restrict__ P,
                                            const bf16_t* __restrict__ vt,
                                            const float* __restrict__ rowsum_part,
                                            float* __restrict__ out,
                                            float* __restrict__ partials) {
    __shared__ __attribute__((aligned(16))) char smem[65536];
    __shared__ float sInv[128];
    int b = blockIdx.x;
    int bn = b & 7, g = b >> 3;
    int bm, s, ns;
    if (g < 8)       { bm = g;                 s = 0;            ns = 1; }
    else if (g < 24) { bm = 8 + (g - 8) / 2;   s = (g - 8) % 2;  ns = 2; }
    else if (g < 48) { bm = 16 + (g - 24) / 3; s = (g - 24) % 3; ns = 3; }
    else             { bm = 24 + (g - 48) / 4; s = (g - 48) % 4; ns = 4; }
    int nk = 2 * (bm + 1);
    int kb0 = s * nk / ns;
    int kb1 = (s + 1) * nk / ns;

    const bf16_t* A = P + (size_t)bm * 128 * 4096;
    const bf16_t* B = vt + (size_t)bn * 128 * 4096;
    if (ns == 1) {
        int tid = threadIdx.x;
        if (tid < 128)
            sInv[tid] = 1.f / sum32(rowsum_part + (size_t)(bm * 128 + tid) * 32);
        // visibility of sInv covered by the K-loop's first barrier
        gemm_tile_bf16<2, float>(A, 4096, B, 4096,
                                 out + (size_t)bm * 128 * 1024 + bn * 128, 1024,
                                 kb0, kb1, 1.f, smem, sInv);
    } else {
        int cum = (bm < 16) ? (bm - 8) * 2
                : (bm < 24) ? 16 + (bm - 16) * 3
                            : 40 + (bm - 24) * 4;
        gemm_tile_bf16<0, float>(A, 4096, B, 4096,
                                 partials + ((size_t)(cum + s) * 8 + bn) * 16384, 128,
                                 kb0, kb1, 1.f, smem, nullptr);
    }
}

// out tiles for bm in [8,31]: sum 2..4 fp32 partials, scale by 1/rowsum.
// Compact 3072 blocks: t = b%192 -> (bm-8, bn); p = b/192 -> tile 16th
// (8 rows x 128 cols per block); float4/thread.
__global__ __launch_bounds__(256) void k_reduce(const float* __restrict__ partials,
                                                const float* __restrict__ rowsum_part,
                                                float* __restrict__ out) {
    int b = blockIdx.x;
    int t = b % 192, p = b / 192;
    int bm = t % 24 + 8, bn = t / 24;
    int ns = (bm < 16) ? 2 : (bm < 24) ? 3 : 4;
    int cum = (bm < 16) ? (bm - 8) * 2
            : (bm < 24) ? 16 + (bm - 16) * 3
                        : 40 + (bm - 24) * 4;
    __shared__ float sInv[8];
    int tid = threadIdx.x;
    if (tid < 8) {
        int row = bm * 128 + p * 8 + tid;
        sInv[tid] = 1.f / sum32(rowsum_part + (size_t)row * 32);
    }
    __syncthreads();

    int idx = p * 1024 + tid * 4;
    int lr = idx >> 7, lc = idx & 127;
    float sx = 0.f, sy = 0.f, sz = 0.f, sw = 0.f;
    for (int u = 0; u < ns; ++u) {
        const float4 v = *(const float4*)(partials + ((size_t)(cum + u) * 8 + bn) * 16384 + idx);
        sx += v.x; sy += v.y; sz += v.z; sw += v.w;
    }
    float inv = sInv[lr - p * 8];
    float4 o = {sx * inv, sy * inv, sz * inv, sw * inv};
    *(float4*)(out + (size_t)(bm * 128 + lr) * 1024 + bn * 128 + lc) = o;
}

// fp32 -> bf16 casts: x -> x_bf, Wq|Wk -> Wqk (concat), Wv -> Wv_bf.
__global__ __launch_bounds__(256) void cast_to_bf16(const float* __restrict__ x,
                                                    const float* __restrict__ Wq,
                                                    const float* __restrict__ Wk,
                                                    const float* __restrict__ Wv,
                                                    bf16_t* __restrict__ xb,
                                                    bf16_t* __restrict__ wqk,
                                                    bf16_t* __restrict__ wv) {
    const int NX = (4096 * 1024) / 4;
    const int NW = (1024 * 1024) / 4;
    int idx = blockIdx.x * 256 + threadIdx.x;
    const float* src;
    bf16_t* dst;
    int off;
    if (idx < NX) {
        src = x; dst = xb; off = idx;
    } else if (idx < NX + NW) {
        src = Wq; dst = wqk; off = idx - NX;
    } else if (idx < NX + 2 * NW) {
        src = Wk; dst = wqk + (size_t)NW * 4; off = idx - NX - NW;
    } else {
        src = Wv; dst = wv; off = idx - NX - 2 * NW;
    }
    float4 f = ((const float4*)src)[off];
    bf16x4v o;
    o.x = (bf16_t)f.x; o.y = (bf16_t)f.y; o.z = (bf16_t)f.z; o.w = (bf16_t)f.w;
    *(bf16x4v*)(dst + (size_t)off * 4) = o;
}

extern "C" void kernel_launch(void* const* d_in, const int* in_sizes, int n_in,
                              void* d_out, int out_size, void* d_ws, size_t ws_size,
                              hipStream_t stream) {
    (void)in_sizes; (void)n_in; (void)out_size; (void)ws_size;
    const float* x  = (const float*)d_in[0];
    const float* Wq = (const float*)d_in[1];
    const float* Wk = (const float*)d_in[2];
    const float* Wv = (const float*)d_in[3];
    float* out = (float*)d_out;

    char* ws = (char*)d_ws;
    bf16_t* xb   = (bf16_t*)(ws + (size_t)0);
    bf16_t* wqk  = (bf16_t*)(ws + ((size_t)8 << 20));
    bf16_t* wvb  = (bf16_t*)(ws + ((size_t)12 << 20));
    u8*     qk   = (u8*)(ws + ((size_t)14 << 20));
    bf16_t* vt   = (bf16_t*)(ws + ((size_t)22 << 20));
    bf16_t* P    = (bf16_t*)(ws + ((size_t)30 << 20));
    float* rowsp = (float*)(ws + ((size_t)62 << 20));
    float* parts = (float*)(ws + ((size_t)64 << 20));

    cast_to_bf16<<<7168, 256, 0, stream>>>(x, Wq, Wk, Wv, xb, wqk, wvb);

    // QK (fp8) = x@[Wq;Wk]^T (512 blocks, 2/CU)
    k_qkv<<<512, 256, 0, stream>>>(xb, wqk, qk);

    // Vt (bf16) = Wv@x^T + P~ = exp((Q@K^T)/32) causal 128x128 (784 blocks)
    k_sv<<<784, 256, 0, stream>>>(xb, wvb, qk, vt, P, rowsp);

    // out = (P~ @ V) * diag(1/rowsum): split-K chunk 16 + partial reduction
    k_pv<<<640, 256, 0, stream>>>(P, vt, rowsp, out, parts);
    k_reduce<<<3072, 256, 0, stream>>>(parts, rowsp, out);
}

// Round 6
// 174.798 us; speedup vs baseline: 1.1833x; 1.0675x over previous
//
#include <hip/hip_runtime.h>
#include <hip/hip_bf16.h>

// Causal attention, S=4096, d=1024, fp32 in/out.
// bf16 MFMA for projections and PV; fp8 e4m3 MFMA (BK=128B) for scores only.
//
// Round-16 (this round): grid/packing fixes; inner loops frozen at r12.
//  - scores tile reverted to r12 dbuf (ring-4 was -2us; pipeline lever closed:
//    2ph ~= counted-2ph ~= ring4 > 8ph at this geometry, per m232 open quad).
//  - k_pv regrid: split-K chunk <=22 -> 63 groups x 8 bn = 504 blocks =
//    SINGLE generation at 2/CU (was 640 -> 1.25 gens, makespan ~2x16 iters).
//    ns: bm 0..10 -> 1 (direct out); 11..21 -> 2; 22..31 -> 3. Max split 22
//    iters. Partial groups 72 -> 52 (-10MB HBM round trip). k_reduce remapped
//    (bm 11..31, 21x8 tiles x16 = 2688 blocks).
//
// Workspace (256 MiB):
//   [0,8M)    x_bf  [4096,1024] bf16
//   [8M,12M)  Wqk   [2048,1024] bf16 (Wq rows 0..1023, Wk rows 1024..2047)
//   [12M,14M) Wv_bf [1024,1024] bf16
//   [14M,22M) QK    [4096,2048] fp8  (Q cols 0..1023, K cols 1024..2047)
//   [22M,30M) Vt    [1024,4096] bf16 (V^T, computed directly as Wv @ x^T)
//   [30M,62M) P~    [4096,4096] bf16 (exp(s/32), masked, unnormalized)
//   [62M,62.5M) rowsum_part [4096][32] fp32 (slot bn; dead slots zeroed)
//   [64M,92M) PV fp32 partials (52 multi-split groups x 8 bn x 64 KB)

typedef __bf16 bf16_t;
typedef __bf16 bf16x4v __attribute__((ext_vector_type(4)));
typedef __bf16 bf16x8 __attribute__((ext_vector_type(8)));
typedef float f32x4 __attribute__((ext_vector_type(4)));
typedef unsigned char u8;
typedef long long i64_t;

#define AS1 __attribute__((address_space(1)))
#define AS3 __attribute__((address_space(3)))
#define WAIT_VMCNT(N) asm volatile("s_waitcnt vmcnt(" #N ")" ::: "memory")
#define BARRIER_RAW() asm volatile("s_barrier" ::: "memory")

__device__ __forceinline__ void async_copy16(const void* g, void* l) {
    // 16B/lane direct global->LDS; LDS dest = wave-uniform base + lane*16
    __builtin_amdgcn_global_load_lds((AS1 void*)(g), (AS3 void*)(l), 16, 0, 0);
}

__device__ __forceinline__ u8 f32_to_fp8(float v) {
    // OCP e4m3 on gfx950 (HW conversion); layout validated in round 6
    return (u8)(__builtin_amdgcn_cvt_pk_fp8_f32(v, v, 0, false) & 0xff);
}

__device__ __forceinline__ void store_conv(float* p, float v) { *p = v; }
__device__ __forceinline__ void store_conv(bf16_t* p, float v) { *p = (bf16_t)v; }
__device__ __forceinline__ void store_conv(u8* p, float v) { *p = f32_to_fp8(v); }

// Sum of 32 consecutive floats (8x float4), for 1/rowsum computation.
__device__ __forceinline__ float sum32(const float* p) {
    const f32x4* v = (const f32x4*)p;
    float s = 0.f;
#pragma unroll
    for (int u = 0; u < 8; ++u) {
        f32x4 a = v[u];
        s += a[0] + a[1] + a[2] + a[3];
    }
    return s;
}

// ---------------- bf16 tile: BM=128, BN=128, BK=64 (validated r12) --------
// Double-buffered staging: A bufs [0,16K),[16K,32K); B bufs [32K,48K),[48K,64K).
// XOR-swizzled LDS (16B chunk b of row r holds k-chunk b^(r&7)).
// Counted-vmcnt 2-barrier K-loop. Epilogue: LDS-bounce -> 16B coalesced stores.
// EPI 0: C = v*alpha | EPI 2: C = v * inv[row] (inv indexed by tile-local row)
template <int EPI, typename OutT>
__device__ __forceinline__ void gemm_tile_bf16(const bf16_t* __restrict__ A, int lda,
                                               const bf16_t* __restrict__ B, int ldb,
                                               OutT* __restrict__ C, int ldc,
                                               int kb0, int kb1, float alpha,
                                               char* __restrict__ smem,
                                               const float* __restrict__ inv) {
    constexpr int BK = 64;
    bf16_t* As = (bf16_t*)smem;            // 2 x 8192 elems (16KB each)
    bf16_t* Bs = (bf16_t*)(smem + 32768);  // 2 x 8192 elems
    const int tid = threadIdx.x;
    const int lane = tid & 63, wave = tid >> 6;
    const int wm = wave >> 1, wn = wave & 1;
    const int q = lane >> 4, l16 = lane & 15;

    f32x4 acc[4][4] = {};

    const bf16_t* aSrc[4];
    const bf16_t* bSrc[4];
    int ldsOff[4];
#pragma unroll
    for (int it = 0; it < 4; ++it) {
        int c = it * 256 + tid;
        int r = c >> 3, b = c & 7;
        int sb = b ^ (r & 7);
        aSrc[it] = A + (size_t)r * lda + sb * 8;
        bSrc[it] = B + (size_t)r * ldb + sb * 8;
        ldsOff[it] = c * 8;
    }

    // prologue: stage first K-step into buffer 0 (8 loads in flight)
    {
        const int k0 = kb0 * BK;
#pragma unroll
        for (int it = 0; it < 4; ++it) async_copy16(aSrc[it] + k0, &As[ldsOff[it]]);
#pragma unroll
        for (int it = 0; it < 4; ++it) async_copy16(bSrc[it] + k0, &Bs[ldsOff[it]]);
    }

    int cur = 0;
    for (int kb = kb0; kb < kb1; ++kb) {
        if (kb + 1 < kb1) {  // prefetch next K-step into alternate buffer
            const int k0 = (kb + 1) * BK;
            const int boff = (cur ^ 1) * 8192;
#pragma unroll
            for (int it = 0; it < 4; ++it) async_copy16(aSrc[it] + k0, &As[boff + ldsOff[it]]);
#pragma unroll
            for (int it = 0; it < 4; ++it) async_copy16(bSrc[it] + k0, &Bs[boff + ldsOff[it]]);
            WAIT_VMCNT(8);   // tile-kb loads (8 oldest) retired; kb+1 in flight
        } else {
            WAIT_VMCNT(0);   // tail: drain everything
        }
        __builtin_amdgcn_sched_barrier(0);
        BARRIER_RAW();       // all waves' tile-kb loads landed
        const bf16_t* Ab = As + cur * 8192;
        const bf16_t* Bb = Bs + cur * 8192;
        __builtin_amdgcn_s_setprio(1);
#pragma unroll
        for (int k2 = 0; k2 < 2; ++k2) {
            bf16x8 af[4], bfr[4];
#pragma unroll
            for (int mt = 0; mt < 4; ++mt) {
                int m = wm * 64 + mt * 16 + l16;
                int blk = (k2 * 4 + q) ^ (m & 7);
                af[mt] = *(const bf16x8*)&Ab[m * BK + blk * 8];
            }
#pragma unroll
            for (int nt = 0; nt < 4; ++nt) {
                int nn = wn * 64 + nt * 16 + l16;
                int blk = (k2 * 4 + q) ^ (nn & 7);
                bfr[nt] = *(const bf16x8*)&Bb[nn * BK + blk * 8];
            }
#pragma unroll
            for (int mt = 0; mt < 4; ++mt)
#pragma unroll
                for (int nt = 0; nt < 4; ++nt)
                    acc[mt][nt] = __builtin_amdgcn_mfma_f32_16x16x32_bf16(
                        af[mt], bfr[nt], acc[mt][nt], 0, 0, 0);
        }
        __builtin_amdgcn_s_setprio(0);
        BARRIER_RAW();       // reads of buf done -> next iter may overwrite
        cur ^= 1;
    }

    // Epilogue: bounce C tile (128x128 OutT) through dead staging LDS.
    // C/D layout: col = lane&15, row = (lane>>4)*4 + reg.
    constexpr int S = (int)sizeof(OutT);
    constexpr int RB = 128 * S;  // bytes per tile row (128/256/512)
    const int row0 = wm * 64, col0 = wn * 64;
#pragma unroll
    for (int mt = 0; mt < 4; ++mt)
#pragma unroll
        for (int nt = 0; nt < 4; ++nt)
#pragma unroll
            for (int r = 0; r < 4; ++r) {
                int lr = row0 + mt * 16 + q * 4 + r;
                int lc = col0 + nt * 16 + l16;
                float v = acc[mt][nt][r];
                v = (EPI == 2) ? v * inv[lr] : v * alpha;
                int cb = (lc * S) >> 4;
                int sw = cb ^ ((lr >> 2) & 7);
                store_conv((OutT*)(smem + lr * RB + (sw << 4) + ((lc * S) & 15)), v);
            }
    __syncthreads();
    // stream out: 16B/thread/pass, fully coalesced (4 threads = one 64B line)
#pragma unroll
    for (int p = 0; p < 4 * S; ++p) {
        int g = p * 4096 + tid * 16;  // linear byte index in tile
        int r = g / RB;
        int wb = g & (RB - 1);
        int sc = (wb >> 4) ^ ((r >> 2) & 7);
        f32x4 val = *(const f32x4*)(smem + r * RB + (sc << 4));
        *(f32x4*)((char*)C + (size_t)r * ((size_t)ldc * S) + wb) = val;
    }
}

// ---------------- fp8 scores tile: 128x128, BK=128 bytes (r12) ------------
// mfma_f32_16x16x32_fp8_fp8 (i64 frags, 8B/lane: m=lane&15, k=quad*8+j).
// Double-buffered staging: A bufs [0,16K),[16K,32K); B bufs [32K,48K),[48K,64K).
// LDS row = 128B = 8 16B chunks, chunk cb of row r at slot cb^(r&7).
// Counted-vmcnt 2-barrier K-loop. Epilogue: P = bf16(exp(v*alpha)) causally
// masked, LDS bounce -> 16B coalesced stores; per-row partial sums into
// `partial` (pre-offset, stride 32 floats).
__device__ __forceinline__ void scores_tile_fp8(const u8* __restrict__ A, int lda,
                                                const u8* __restrict__ B, int ldb,
                                                bf16_t* __restrict__ C, int ldc,
                                                float alpha, char* __restrict__ smem,
                                                float* __restrict__ partial,
                                                int gr0, int gc0) {
    u8* As = (u8*)smem;
    u8* Bs = (u8*)(smem + 32768);
    const int tid = threadIdx.x;
    const int lane = tid & 63, wave = tid >> 6;
    const int wm = wave >> 1, wn = wave & 1;
    const int q = lane >> 4, l16 = lane & 15;

    f32x4 acc[4][4] = {};

    const u8* aSrc[4];
    const u8* bSrc[4];
    int ldsOff[4];
#pragma unroll
    for (int it = 0; it < 4; ++it) {
        int c = it * 256 + tid;
        int r = c >> 3, b = c & 7;
        int sb = b ^ (r & 7);
        aSrc[it] = A + (size_t)r * lda + sb * 16;
        bSrc[it] = B + (size_t)r * ldb + sb * 16;
        ldsOff[it] = c * 16;
    }

    // prologue: stage k-block 0 into buffer 0
    {
#pragma unroll
        for (int it = 0; it < 4; ++it) async_copy16(aSrc[it], &As[ldsOff[it]]);
#pragma unroll
        for (int it = 0; it < 4; ++it) async_copy16(bSrc[it], &Bs[ldsOff[it]]);
    }

    int cur = 0;
    for (int kb = 0; kb < 8; ++kb) {
        if (kb < 7) {  // prefetch next k-block
            const int k0 = (kb + 1) * 128;
            const int boff = (cur ^ 1) * 16384;
#pragma unroll
            for (int it = 0; it < 4; ++it) async_copy16(aSrc[it] + k0, &As[boff + ldsOff[it]]);
#pragma unroll
            for (int it = 0; it < 4; ++it) async_copy16(bSrc[it] + k0, &Bs[boff + ldsOff[it]]);
            WAIT_VMCNT(8);
        } else {
            WAIT_VMCNT(0);
        }
        __builtin_amdgcn_sched_barrier(0);
        BARRIER_RAW();
        const u8* Ab = As + cur * 16384;
        const u8* Bb = Bs + cur * 16384;
        __builtin_amdgcn_s_setprio(1);
#pragma unroll
        for (int k2 = 0; k2 < 4; ++k2) {
            i64_t af[4], bfr[4];
            const int cb = 2 * k2 + (q >> 1), co = (q & 1) * 8;
#pragma unroll
            for (int mt = 0; mt < 4; ++mt) {
                int m = wm * 64 + mt * 16 + l16;
                af[mt] = *(const i64_t*)&Ab[m * 128 + ((cb ^ (m & 7)) << 4) + co];
            }
#pragma unroll
            for (int nt = 0; nt < 4; ++nt) {
                int nn = wn * 64 + nt * 16 + l16;
                bfr[nt] = *(const i64_t*)&Bb[nn * 128 + ((cb ^ (nn & 7)) << 4) + co];
            }
#pragma unroll
            for (int mt = 0; mt < 4; ++mt)
#pragma unroll
                for (int nt = 0; nt < 4; ++nt)
                    acc[mt][nt] = __builtin_amdgcn_mfma_f32_16x16x32_fp8_fp8(
                        af[mt], bfr[nt], acc[mt][nt], 0, 0, 0);
        }
        __builtin_amdgcn_s_setprio(0);
        BARRIER_RAW();
        cur ^= 1;
    }

    // Epilogue: P = exp(v*alpha) masked -> LDS bounce (bf16, 32KB) + per-row
    // sums via 16-lane shfl into sred (smem+32K, disjoint from bounce).
    float* sred = (float*)(smem + 32768);
    const int row0 = wm * 64, col0 = wn * 64;
    float esum[4][4];
#pragma unroll
    for (int mt = 0; mt < 4; ++mt)
#pragma unroll
        for (int r = 0; r < 4; ++r) esum[mt][r] = 0.f;
#pragma unroll
    for (int mt = 0; mt < 4; ++mt)
#pragma unroll
        for (int nt = 0; nt < 4; ++nt)
#pragma unroll
            for (int r = 0; r < 4; ++r) {
                int lr = row0 + mt * 16 + q * 4 + r;
                int lc = col0 + nt * 16 + l16;
                float pe = (gc0 + lc > gr0 + lr) ? 0.f : __expf(acc[mt][nt][r] * alpha);
                esum[mt][r] += pe;
                int sw = (lc >> 3) ^ ((lr >> 2) & 7);
                *(bf16_t*)(smem + lr * 256 + (sw << 4) + ((lc * 2) & 15)) = (bf16_t)pe;
            }
#pragma unroll
    for (int mt = 0; mt < 4; ++mt)
#pragma unroll
        for (int r = 0; r < 4; ++r) {
#pragma unroll
            for (int off = 1; off < 16; off <<= 1)
                esum[mt][r] += __shfl_xor(esum[mt][r], off, 64);
            if (l16 == 0) sred[(row0 + mt * 16 + q * 4 + r) * 2 + wn] = esum[mt][r];
        }
    __syncthreads();
    // stream P tile out: 8 passes x 16B/thread, coalesced 256B rows
#pragma unroll
    for (int p = 0; p < 8; ++p) {
        int g = p * 4096 + tid * 16;
        int r = g >> 8;
        int wb = g & 255;
        int sc = (wb >> 4) ^ ((r >> 2) & 7);
        f32x4 val = *(const f32x4*)(smem + r * 256 + (sc << 4));
        *(f32x4*)((char*)C + (size_t)r * ((size_t)ldc * 2) + wb) = val;
    }
    if (tid < 128) partial[(size_t)tid * 32] = sred[tid * 2] + sred[tid * 2 + 1];
}

// QK projection only: 512 uniform blocks (2/CU, exactly 1 generation).
// QK = x @ [Wq;Wk]^T -> [4096,2048] fp8.
__global__ __launch_bounds__(256) void k_qkv(const bf16_t* __restrict__ xb,
                                             const bf16_t* __restrict__ wqk,
                                             u8* __restrict__ qk) {
    __shared__ __attribute__((aligned(16))) char smem[65536];
    int b = blockIdx.x;
    int bm = b & 31, bn = b >> 5;  // bn 0..15
    gemm_tile_bf16<0, u8>(xb + (size_t)bm * 128 * 1024, 1024,
                          wqk + (size_t)bn * 128 * 1024, 1024,
                          qk + (size_t)bm * 128 * 2048 + bn * 128, 2048,
                          0, 16, 1.f, smem, nullptr);
}

// Merged dispatch, 784 blocks (2/CU resident):
//   b in [0,256):   Vt = Wv @ x^T [1024,4096] bf16 (16 bf16 iters)
//   b in [256,784): P~ = exp((Q@K^T)/32) causal 128x128 tiles, fp8, 8 iters;
//     compact tri grid t = bm(bm+1)/2 + bn (528 tiles); emits per-row partial
//     sums; diagonal tiles (bn==bm) zero dead slots [bm+1,32).
__global__ __launch_bounds__(256) void k_sv(const bf16_t* __restrict__ xb,
                                            const bf16_t* __restrict__ wvb,
                                            const u8* __restrict__ qk,
                                            bf16_t* __restrict__ vt,
                                            bf16_t* __restrict__ P,
                                            float* __restrict__ rowsum_part) {
    __shared__ __attribute__((aligned(16))) char smem[65536];
    int b = blockIdx.x;
    if (b < 256) {
        int bm = b & 7, bn = b >> 3;  // bn 0..31
        gemm_tile_bf16<0, bf16_t>(wvb + (size_t)bm * 128 * 1024, 1024,
                                  xb + (size_t)bn * 128 * 1024, 1024,
                                  vt + (size_t)bm * 128 * 4096 + bn * 128, 4096,
                                  0, 16, 1.f, smem, nullptr);
        return;
    }
    int t = b - 256;  // 0..527
    int bm = (int)((sqrtf(8.f * (float)t + 1.f) - 1.f) * 0.5f);
    while (bm * (bm + 1) / 2 > t) --bm;
    while ((bm + 1) * (bm + 2) / 2 <= t) ++bm;
    int bn = t - bm * (bm + 1) / 2;  // 0..bm
    scores_tile_fp8(qk + (size_t)bm * 128 * 2048, 2048,
                    qk + 1024 + (size_t)bn * 128 * 2048, 2048,
                    P + (size_t)bm * 128 * 4096 + bn * 128, 4096,
                    0.03125f, smem,
                    rowsum_part + (size_t)bm * 128 * 32 + bn,
                    bm * 128, bn * 128);
    if (bn == bm) {  // zero dead rowsum slots for this row block
        float* rp = rowsum_part + (size_t)bm * 128 * 32;
        int tid = threadIdx.x;
        for (int r = tid >> 4; r < 128; r += 16)
            for (int u = bm + 1 + (tid & 15); u < 32; u += 16)
                rp[r * 32 + u] = 0.f;
    }
}

// O = (P~ @ V) * diag(1/rowsum), bf16, BK=64: nk = 2(bm+1) iters.
// Split-K chunk <=22: ns = 1 (bm 0..10) / 2 (bm 11..21) / 3 (bm 22..31).
// Groups: 11 + 22 + 30 = 63; x 8 bn = 504 blocks = ONE generation at 2/CU.
// Single-split computes 1/rowsum into LDS and stores direct; multi-split
// writes fp32 partials (16B coalesced via bounce) for k_reduce.
__global__ __launch_bounds__(256) void k_pv(const bf16_t* __restrict__ P,
                                            const bf16_t* __restrict__ vt,
                                            const float* __restrict__ rowsum_part,
                                            float* __restrict__ out,
                                            float* __restrict__ partials) {
    __shared__ __attribute__((aligned(16))) char smem[65536];
    __shared__ float sInv[128];
    int b = blockIdx.x;
    int bn = b & 7, g = b >> 3;  // g 0..62
    int bm, s, ns;
    if (g < 11)      { bm = g;                  s = 0;             ns = 1; }
    else if (g < 33) { bm = 11 + (g - 11) / 2;  s = (g - 11) % 2;  ns = 2; }
    else             { bm = 22 + (g - 33) / 3;  s = (g - 33) % 3;  ns = 3; }
    int nk = 2 * (bm + 1);
    int kb0 = s * nk / ns;
    int kb1 = (s + 1) * nk / ns;

    const bf16_t* A = P + (size_t)bm * 128 * 4096;
    const bf16_t* B = vt + (size_t)bn * 128 * 4096;
    if (ns == 1) {
        int tid = threadIdx.x;
        if (tid < 128)
            sInv[tid] = 1.f / sum32(rowsum_part + (size_t)(bm * 128 + tid) * 32);
        // visibility of sInv covered by the K-loop's first barrier
        gemm_tile_bf16<2, float>(A, 4096, B, 4096,
                                 out + (size_t)bm * 128 * 1024 + bn * 128, 1024,
                                 kb0, kb1, 1.f, smem, sInv);
    } else {
        int cum = (bm < 22) ? (bm - 11) * 2 : 22 + (bm - 22) * 3;
        gemm_tile_bf16<0, float>(A, 4096, B, 4096,
                                 partials + ((size_t)(cum + s) * 8 + bn) * 16384, 128,
                                 kb0, kb1, 1.f, smem, nullptr);
    }
}

// out tiles for bm in [11,31]: sum 2..3 fp32 partials, scale by 1/rowsum.
// 21 bm x 8 bn = 168 tiles; x16 sub-blocks (8 rows x 128 cols, float4/thr)
// = 2688 blocks.
__global__ __launch_bounds__(256) void k_reduce(const float* __restrict__ partials,
                                                const float* __restrict__ rowsum_part,
                                                float* __restrict__ out) {
    int b = blockIdx.x;
    int t = b % 168, p = b / 168;
    int bm = 11 + t % 21, bn = t / 21;
    int ns = (bm < 22) ? 2 : 3;
    int cum = (bm < 22) ? (bm - 11) * 2 : 22 + (bm - 22) * 3;
    __shared__ float sInv[8];
    int tid = threadIdx.x;
    if (tid < 8) {
        int row = bm * 128 + p * 8 + tid;
        sInv[tid] = 1.f / sum32(rowsum_part + (size_t)row * 32);
    }
    __syncthreads();

    int idx = p * 1024 + tid * 4;
    int lr = idx >> 7, lc = idx & 127;
    float sx = 0.f, sy = 0.f, sz = 0.f, sw = 0.f;
    for (int u = 0; u < ns; ++u) {
        const float4 v = *(const float4*)(partials + ((size_t)(cum + u) * 8 + bn) * 16384 + idx);
        sx += v.x; sy += v.y; sz += v.z; sw += v.w;
    }
    float inv = sInv[lr - p * 8];
    float4 o = {sx * inv, sy * inv, sz * inv, sw * inv};
    *(float4*)(out + (size_t)(bm * 128 + lr) * 1024 + bn * 128 + lc) = o;
}

// fp32 -> bf16 casts: x -> x_bf, Wq|Wk -> Wqk (concat), Wv -> Wv_bf.
__global__ __launch_bounds__(256) void cast_to_bf16(const float* __restrict__ x,
                                                    const float* __restrict__ Wq,
                                                    const float* __restrict__ Wk,
                                                    const float* __restrict__ Wv,
                                                    bf16_t* __restrict__ xb,
                                                    bf16_t* __restrict__ wqk,
                                                    bf16_t* __restrict__ wv) {
    const int NX = (4096 * 1024) / 4;
    const int NW = (1024 * 1024) / 4;
    int idx = blockIdx.x * 256 + threadIdx.x;
    const float* src;
    bf16_t* dst;
    int off;
    if (idx < NX) {
        src = x; dst = xb; off = idx;
    } else if (idx < NX + NW) {
        src = Wq; dst = wqk; off = idx - NX;
    } else if (idx < NX + 2 * NW) {
        src = Wk; dst = wqk + (size_t)NW * 4; off = idx - NX - NW;
    } else {
        src = Wv; dst = wv; off = idx - NX - 2 * NW;
    }
    float4 f = ((const float4*)src)[off];
    bf16x4v o;
    o.x = (bf16_t)f.x; o.y = (bf16_t)f.y; o.z = (bf16_t)f.z; o.w = (bf16_t)f.w;
    *(bf16x4v*)(dst + (size_t)off * 4) = o;
}

extern "C" void kernel_launch(void* const* d_in, const int* in_sizes, int n_in,
                              void* d_out, int out_size, void* d_ws, size_t ws_size,
                              hipStream_t stream) {
    (void)in_sizes; (void)n_in; (void)out_size; (void)ws_size;
    const float* x  = (const float*)d_in[0];
    const float* Wq = (const float*)d_in[1];
    const float* Wk = (const float*)d_in[2];
    const float* Wv = (const float*)d_in[3];
    float* out = (float*)d_out;

    char* ws = (char*)d_ws;
    bf16_t* xb   = (bf16_t*)(ws + (size_t)0);
    bf16_t* wqk  = (bf16_t*)(ws + ((size_t)8 << 20));
    bf16_t* wvb  = (bf16_t*)(ws + ((size_t)12 << 20));
    u8*     qk   = (u8*)(ws + ((size_t)14 << 20));
    bf16_t* vt   = (bf16_t*)(ws + ((size_t)22 << 20));
    bf16_t* P    = (bf16_t*)(ws + ((size_t)30 << 20));
    float* rowsp = (float*)(ws + ((size_t)62 << 20));
    float* parts = (float*)(ws + ((size_t)64 << 20));

    cast_to_bf16<<<7168, 256, 0, stream>>>(x, Wq, Wk, Wv, xb, wqk, wvb);

    // QK (fp8) = x@[Wq;Wk]^T (512 blocks, 2/CU, 1 generation)
    k_qkv<<<512, 256, 0, stream>>>(xb, wqk, qk);

    // Vt (bf16) = Wv@x^T + P~ = exp((Q@K^T)/32) causal 128x128 (784 blocks)
    k_sv<<<784, 256, 0, stream>>>(xb, wvb, qk, vt, P, rowsp);

    // out = (P~ @ V) * diag(1/rowsum): split-K chunk <=22 (504 blocks, 1 gen)
    k_pv<<<504, 256, 0, stream>>>(P, vt, rowsp, out, parts);
    k_reduce<<<2688, 256, 0, stream>>>(parts, rowsp, out);
}

// Round 7
// 165.611 us; speedup vs baseline: 1.2489x; 1.0555x over previous
//
#include <hip/hip_runtime.h>
#include <hip/hip_bf16.h>

// Causal attention, S=4096, d=1024, fp32 in/out.
// bf16 MFMA for projections and PV; fp8 e4m3 MFMA (BK=128B) for scores only.
//
// Round-17 (this round): k_sv occupancy fix. 784 blocks @ 64KB LDS = 2/CU =
// 2 generations (76% packing; Occ 13.5%). Shrink k_sv tiles to single-buffer
// 33KB (m97-proven structure: stage -> sync -> compute -> sync; cross-block
// wave overlap does the hiding, m114/m97 912TF @ 3 blocks/CU) + launch_bounds
// (256,4) -> 4 blocks/CU -> single generation in 1024 slots.
// k_qkv (512 = 2x256 exact) and k_pv (504) keep r12 dbuf tiles: their avg
// concurrency is 2/CU regardless, no packing gain available.
//
// Round-16: k_pv regrid 504 blocks/1gen (+12us, validated packing theory).
//
// Workspace (256 MiB):
//   [0,8M)    x_bf  [4096,1024] bf16
//   [8M,12M)  Wqk   [2048,1024] bf16 (Wq rows 0..1023, Wk rows 1024..2047)
//   [12M,14M) Wv_bf [1024,1024] bf16
//   [14M,22M) QK    [4096,2048] fp8  (Q cols 0..1023, K cols 1024..2047)
//   [22M,30M) Vt    [1024,4096] bf16 (V^T, computed directly as Wv @ x^T)
//   [30M,62M) P~    [4096,4096] bf16 (exp(s/32), masked, unnormalized)
//   [62M,62.5M) rowsum_part [4096][32] fp32 (slot bn; dead slots zeroed)
//   [64M,92M) PV fp32 partials (52 multi-split groups x 8 bn x 64 KB)

typedef __bf16 bf16_t;
typedef __bf16 bf16x4v __attribute__((ext_vector_type(4)));
typedef __bf16 bf16x8 __attribute__((ext_vector_type(8)));
typedef float f32x4 __attribute__((ext_vector_type(4)));
typedef unsigned char u8;
typedef long long i64_t;

#define AS1 __attribute__((address_space(1)))
#define AS3 __attribute__((address_space(3)))
#define WAIT_VMCNT(N) asm volatile("s_waitcnt vmcnt(" #N ")" ::: "memory")
#define BARRIER_RAW() asm volatile("s_barrier" ::: "memory")

__device__ __forceinline__ void async_copy16(const void* g, void* l) {
    // 16B/lane direct global->LDS; LDS dest = wave-uniform base + lane*16
    __builtin_amdgcn_global_load_lds((AS1 void*)(g), (AS3 void*)(l), 16, 0, 0);
}

__device__ __forceinline__ u8 f32_to_fp8(float v) {
    // OCP e4m3 on gfx950 (HW conversion); layout validated in round 6
    return (u8)(__builtin_amdgcn_cvt_pk_fp8_f32(v, v, 0, false) & 0xff);
}

__device__ __forceinline__ void store_conv(float* p, float v) { *p = v; }
__device__ __forceinline__ void store_conv(bf16_t* p, float v) { *p = (bf16_t)v; }
__device__ __forceinline__ void store_conv(u8* p, float v) { *p = f32_to_fp8(v); }

// Sum of 32 consecutive floats (8x float4), for 1/rowsum computation.
__device__ __forceinline__ float sum32(const float* p) {
    const f32x4* v = (const f32x4*)p;
    float s = 0.f;
#pragma unroll
    for (int u = 0; u < 8; ++u) {
        f32x4 a = v[u];
        s += a[0] + a[1] + a[2] + a[3];
    }
    return s;
}

// ---------------- bf16 tile: BM=128, BN=128, BK=64 (r12, dbuf 64KB) -------
// Double-buffered staging: A bufs [0,16K),[16K,32K); B bufs [32K,48K),[48K,64K).
// XOR-swizzled LDS (16B chunk b of row r holds k-chunk b^(r&7)).
// Counted-vmcnt 2-barrier K-loop. Epilogue: LDS-bounce -> 16B coalesced stores.
// EPI 0: C = v*alpha | EPI 2: C = v * inv[row] (inv indexed by tile-local row)
template <int EPI, typename OutT>
__device__ __forceinline__ void gemm_tile_bf16(const bf16_t* __restrict__ A, int lda,
                                               const bf16_t* __restrict__ B, int ldb,
                                               OutT* __restrict__ C, int ldc,
                                               int kb0, int kb1, float alpha,
                                               char* __restrict__ smem,
                                               const float* __restrict__ inv) {
    constexpr int BK = 64;
    bf16_t* As = (bf16_t*)smem;            // 2 x 8192 elems (16KB each)
    bf16_t* Bs = (bf16_t*)(smem + 32768);  // 2 x 8192 elems
    const int tid = threadIdx.x;
    const int lane = tid & 63, wave = tid >> 6;
    const int wm = wave >> 1, wn = wave & 1;
    const int q = lane >> 4, l16 = lane & 15;

    f32x4 acc[4][4] = {};

    const bf16_t* aSrc[4];
    const bf16_t* bSrc[4];
    int ldsOff[4];
#pragma unroll
    for (int it = 0; it < 4; ++it) {
        int c = it * 256 + tid;
        int r = c >> 3, b = c & 7;
        int sb = b ^ (r & 7);
        aSrc[it] = A + (size_t)r * lda + sb * 8;
        bSrc[it] = B + (size_t)r * ldb + sb * 8;
        ldsOff[it] = c * 8;
    }

    // prologue: stage first K-step into buffer 0 (8 loads in flight)
    {
        const int k0 = kb0 * BK;
#pragma unroll
        for (int it = 0; it < 4; ++it) async_copy16(aSrc[it] + k0, &As[ldsOff[it]]);
#pragma unroll
        for (int it = 0; it < 4; ++it) async_copy16(bSrc[it] + k0, &Bs[ldsOff[it]]);
    }

    int cur = 0;
    for (int kb = kb0; kb < kb1; ++kb) {
        if (kb + 1 < kb1) {  // prefetch next K-step into alternate buffer
            const int k0 = (kb + 1) * BK;
            const int boff = (cur ^ 1) * 8192;
#pragma unroll
            for (int it = 0; it < 4; ++it) async_copy16(aSrc[it] + k0, &As[boff + ldsOff[it]]);
#pragma unroll
            for (int it = 0; it < 4; ++it) async_copy16(bSrc[it] + k0, &Bs[boff + ldsOff[it]]);
            WAIT_VMCNT(8);   // tile-kb loads (8 oldest) retired; kb+1 in flight
        } else {
            WAIT_VMCNT(0);   // tail: drain everything
        }
        __builtin_amdgcn_sched_barrier(0);
        BARRIER_RAW();       // all waves' tile-kb loads landed
        const bf16_t* Ab = As + cur * 8192;
        const bf16_t* Bb = Bs + cur * 8192;
        __builtin_amdgcn_s_setprio(1);
#pragma unroll
        for (int k2 = 0; k2 < 2; ++k2) {
            bf16x8 af[4], bfr[4];
#pragma unroll
            for (int mt = 0; mt < 4; ++mt) {
                int m = wm * 64 + mt * 16 + l16;
                int blk = (k2 * 4 + q) ^ (m & 7);
                af[mt] = *(const bf16x8*)&Ab[m * BK + blk * 8];
            }
#pragma unroll
            for (int nt = 0; nt < 4; ++nt) {
                int nn = wn * 64 + nt * 16 + l16;
                int blk = (k2 * 4 + q) ^ (nn & 7);
                bfr[nt] = *(const bf16x8*)&Bb[nn * BK + blk * 8];
            }
#pragma unroll
            for (int mt = 0; mt < 4; ++mt)
#pragma unroll
                for (int nt = 0; nt < 4; ++nt)
                    acc[mt][nt] = __builtin_amdgcn_mfma_f32_16x16x32_bf16(
                        af[mt], bfr[nt], acc[mt][nt], 0, 0, 0);
        }
        __builtin_amdgcn_s_setprio(0);
        BARRIER_RAW();       // reads of buf done -> next iter may overwrite
        cur ^= 1;
    }

    // Epilogue: bounce C tile (128x128 OutT) through dead staging LDS.
    // C/D layout: col = lane&15, row = (lane>>4)*4 + reg.
    constexpr int S = (int)sizeof(OutT);
    constexpr int RB = 128 * S;  // bytes per tile row (128/256/512)
    const int row0 = wm * 64, col0 = wn * 64;
#pragma unroll
    for (int mt = 0; mt < 4; ++mt)
#pragma unroll
        for (int nt = 0; nt < 4; ++nt)
#pragma unroll
            for (int r = 0; r < 4; ++r) {
                int lr = row0 + mt * 16 + q * 4 + r;
                int lc = col0 + nt * 16 + l16;
                float v = acc[mt][nt][r];
                v = (EPI == 2) ? v * inv[lr] : v * alpha;
                int cb = (lc * S) >> 4;
                int sw = cb ^ ((lr >> 2) & 7);
                store_conv((OutT*)(smem + lr * RB + (sw << 4) + ((lc * S) & 15)), v);
            }
    __syncthreads();
    // stream out: 16B/thread/pass, fully coalesced (4 threads = one 64B line)
#pragma unroll
    for (int p = 0; p < 4 * S; ++p) {
        int g = p * 4096 + tid * 16;  // linear byte index in tile
        int r = g / RB;
        int wb = g & (RB - 1);
        int sc = (wb >> 4) ^ ((r >> 2) & 7);
        f32x4 val = *(const f32x4*)(smem + r * RB + (sc << 4));
        *(f32x4*)((char*)C + (size_t)r * ((size_t)ldc * S) + wb) = val;
    }
}

// ---------------- bf16 tile, single-buffer 32KB (m97 structure) -----------
// As [0,16K), Bs [16K,32K). Per iter: stage 8 loads -> __syncthreads (vmcnt0
// drain) -> ds_read + 32 MFMA -> __syncthreads (WAR). 4 blocks/CU resident;
// cross-block wave overlap hides the drain (m97: 912 TF at 3/CU).
// Epilogue: 32KB LDS bounce (OutT bf16). Accumulation order identical to r12.
__device__ __forceinline__ void gemm_tile_bf16_sb(const bf16_t* __restrict__ A, int lda,
                                                  const bf16_t* __restrict__ B, int ldb,
                                                  bf16_t* __restrict__ C, int ldc,
                                                  int kb1, char* __restrict__ smem) {
    constexpr int BK = 64;
    bf16_t* As = (bf16_t*)smem;            // 8192 elems (16KB)
    bf16_t* Bs = (bf16_t*)(smem + 16384);  // 8192 elems
    const int tid = threadIdx.x;
    const int lane = tid & 63, wave = tid >> 6;
    const int wm = wave >> 1, wn = wave & 1;
    const int q = lane >> 4, l16 = lane & 15;

    f32x4 acc[4][4] = {};

    const bf16_t* aSrc[4];
    const bf16_t* bSrc[4];
    int ldsOff[4];
#pragma unroll
    for (int it = 0; it < 4; ++it) {
        int c = it * 256 + tid;
        int r = c >> 3, b = c & 7;
        int sb = b ^ (r & 7);
        aSrc[it] = A + (size_t)r * lda + sb * 8;
        bSrc[it] = B + (size_t)r * ldb + sb * 8;
        ldsOff[it] = c * 8;
    }

    for (int kb = 0; kb < kb1; ++kb) {
        const int k0 = kb * BK;
#pragma unroll
        for (int it = 0; it < 4; ++it) async_copy16(aSrc[it] + k0, &As[ldsOff[it]]);
#pragma unroll
        for (int it = 0; it < 4; ++it) async_copy16(bSrc[it] + k0, &Bs[ldsOff[it]]);
        __syncthreads();
        __builtin_amdgcn_s_setprio(1);
#pragma unroll
        for (int k2 = 0; k2 < 2; ++k2) {
            bf16x8 af[4], bfr[4];
#pragma unroll
            for (int mt = 0; mt < 4; ++mt) {
                int m = wm * 64 + mt * 16 + l16;
                int blk = (k2 * 4 + q) ^ (m & 7);
                af[mt] = *(const bf16x8*)&As[m * BK + blk * 8];
            }
#pragma unroll
            for (int nt = 0; nt < 4; ++nt) {
                int nn = wn * 64 + nt * 16 + l16;
                int blk = (k2 * 4 + q) ^ (nn & 7);
                bfr[nt] = *(const bf16x8*)&Bs[nn * BK + blk * 8];
            }
#pragma unroll
            for (int mt = 0; mt < 4; ++mt)
#pragma unroll
                for (int nt = 0; nt < 4; ++nt)
                    acc[mt][nt] = __builtin_amdgcn_mfma_f32_16x16x32_bf16(
                        af[mt], bfr[nt], acc[mt][nt], 0, 0, 0);
        }
        __builtin_amdgcn_s_setprio(0);
        __syncthreads();  // reads done -> next stage may overwrite
    }

    // Epilogue: bounce C tile (128x128 bf16, 32KB) through staging LDS.
    constexpr int RB = 256;
    const int row0 = wm * 64, col0 = wn * 64;
#pragma unroll
    for (int mt = 0; mt < 4; ++mt)
#pragma unroll
        for (int nt = 0; nt < 4; ++nt)
#pragma unroll
            for (int r = 0; r < 4; ++r) {
                int lr = row0 + mt * 16 + q * 4 + r;
                int lc = col0 + nt * 16 + l16;
                int cb = (lc * 2) >> 4;
                int sw = cb ^ ((lr >> 2) & 7);
                *(bf16_t*)(smem + lr * RB + (sw << 4) + ((lc * 2) & 15)) =
                    (bf16_t)acc[mt][nt][r];
            }
    __syncthreads();
#pragma unroll
    for (int p = 0; p < 8; ++p) {
        int g = p * 4096 + tid * 16;
        int r = g >> 8, wb = g & 255;
        int sc = (wb >> 4) ^ ((r >> 2) & 7);
        f32x4 val = *(const f32x4*)(smem + r * RB + (sc << 4));
        *(f32x4*)((char*)C + (size_t)r * ((size_t)ldc * 2) + wb) = val;
    }
}

// ---------------- fp8 scores tile, single-buffer 32KB ---------------------
// As [0,16K), Bs [16K,32K); LDS row = 128B = 8 chunks, chunk cb of row r at
// slot cb^(r&7). m97-style loop (8 iters). Epilogue identical to r12: P =
// bf16(exp(v*alpha)) masked, 32KB bounce + sred at smem+32768 (1KB), 16B
// coalesced stores; per-row partial sums into `partial` (stride 32 floats).
__device__ __forceinline__ void scores_tile_fp8_sb(const u8* __restrict__ A, int lda,
                                                   const u8* __restrict__ B, int ldb,
                                                   bf16_t* __restrict__ C, int ldc,
                                                   float alpha, char* __restrict__ smem,
                                                   float* __restrict__ partial,
                                                   int gr0, int gc0) {
    u8* As = (u8*)smem;
    u8* Bs = (u8*)(smem + 16384);
    const int tid = threadIdx.x;
    const int lane = tid & 63, wave = tid >> 6;
    const int wm = wave >> 1, wn = wave & 1;
    const int q = lane >> 4, l16 = lane & 15;

    f32x4 acc[4][4] = {};

    const u8* aSrc[4];
    const u8* bSrc[4];
    int ldsOff[4];
#pragma unroll
    for (int it = 0; it < 4; ++it) {
        int c = it * 256 + tid;
        int r = c >> 3, b = c & 7;
        int sb = b ^ (r & 7);
        aSrc[it] = A + (size_t)r * lda + sb * 16;
        bSrc[it] = B + (size_t)r * ldb + sb * 16;
        ldsOff[it] = c * 16;
    }

    for (int kb = 0; kb < 8; ++kb) {
        const int k0 = kb * 128;
#pragma unroll
        for (int it = 0; it < 4; ++it) async_copy16(aSrc[it] + k0, &As[ldsOff[it]]);
#pragma unroll
        for (int it = 0; it < 4; ++it) async_copy16(bSrc[it] + k0, &Bs[ldsOff[it]]);
        __syncthreads();
        __builtin_amdgcn_s_setprio(1);
#pragma unroll
        for (int k2 = 0; k2 < 4; ++k2) {
            i64_t af[4], bfr[4];
            const int cb = 2 * k2 + (q >> 1), co = (q & 1) * 8;
#pragma unroll
            for (int mt = 0; mt < 4; ++mt) {
                int m = wm * 64 + mt * 16 + l16;
                af[mt] = *(const i64_t*)&As[m * 128 + ((cb ^ (m & 7)) << 4) + co];
            }
#pragma unroll
            for (int nt = 0; nt < 4; ++nt) {
                int nn = wn * 64 + nt * 16 + l16;
                bfr[nt] = *(const i64_t*)&Bs[nn * 128 + ((cb ^ (nn & 7)) << 4) + co];
            }
#pragma unroll
            for (int mt = 0; mt < 4; ++mt)
#pragma unroll
                for (int nt = 0; nt < 4; ++nt)
                    acc[mt][nt] = __builtin_amdgcn_mfma_f32_16x16x32_fp8_fp8(
                        af[mt], bfr[nt], acc[mt][nt], 0, 0, 0);
        }
        __builtin_amdgcn_s_setprio(0);
        __syncthreads();
    }

    // Epilogue: P = exp(v*alpha) masked -> LDS bounce (bf16, 32KB) + per-row
    // sums via 16-lane shfl into sred (smem+32K, disjoint from bounce).
    float* sred = (float*)(smem + 32768);
    const int row0 = wm * 64, col0 = wn * 64;
    float esum[4][4];
#pragma unroll
    for (int mt = 0; mt < 4; ++mt)
#pragma unroll
        for (int r = 0; r < 4; ++r) esum[mt][r] = 0.f;
#pragma unroll
    for (int mt = 0; mt < 4; ++mt)
#pragma unroll
        for (int nt = 0; nt < 4; ++nt)
#pragma unroll
            for (int r = 0; r < 4; ++r) {
                int lr = row0 + mt * 16 + q * 4 + r;
                int lc = col0 + nt * 16 + l16;
                float pe = (gc0 + lc > gr0 + lr) ? 0.f : __expf(acc[mt][nt][r] * alpha);
                esum[mt][r] += pe;
                int sw = (lc >> 3) ^ ((lr >> 2) & 7);
                *(bf16_t*)(smem + lr * 256 + (sw << 4) + ((lc * 2) & 15)) = (bf16_t)pe;
            }
#pragma unroll
    for (int mt = 0; mt < 4; ++mt)
#pragma unroll
        for (int r = 0; r < 4; ++r) {
#pragma unroll
            for (int off = 1; off < 16; off <<= 1)
                esum[mt][r] += __shfl_xor(esum[mt][r], off, 64);
            if (l16 == 0) sred[(row0 + mt * 16 + q * 4 + r) * 2 + wn] = esum[mt][r];
        }
    __syncthreads();
    // stream P tile out: 8 passes x 16B/thread, coalesced 256B rows
#pragma unroll
    for (int p = 0; p < 8; ++p) {
        int g = p * 4096 + tid * 16;
        int r = g >> 8;
        int wb = g & 255;
        int sc = (wb >> 4) ^ ((r >> 2) & 7);
        f32x4 val = *(const f32x4*)(smem + r * 256 + (sc << 4));
        *(f32x4*)((char*)C + (size_t)r * ((size_t)ldc * 2) + wb) = val;
    }
    if (tid < 128) partial[(size_t)tid * 32] = sred[tid * 2] + sred[tid * 2 + 1];
}

// QK projection only: 512 uniform blocks (2/CU, exactly 1 generation).
// QK = x @ [Wq;Wk]^T -> [4096,2048] fp8.
__global__ __launch_bounds__(256) void k_qkv(const bf16_t* __restrict__ xb,
                                             const bf16_t* __restrict__ wqk,
                                             u8* __restrict__ qk) {
    __shared__ __attribute__((aligned(16))) char smem[65536];
    int b = blockIdx.x;
    int bm = b & 31, bn = b >> 5;  // bn 0..15
    gemm_tile_bf16<0, u8>(xb + (size_t)bm * 128 * 1024, 1024,
                          wqk + (size_t)bn * 128 * 1024, 1024,
                          qk + (size_t)bm * 128 * 2048 + bn * 128, 2048,
                          0, 16, 1.f, smem, nullptr);
}

// Merged dispatch, 784 blocks @ 33KB LDS + launch_bounds(256,4) = 4/CU ->
// SINGLE generation in 1024 slots:
//   b in [0,256):   Vt = Wv @ x^T [1024,4096] bf16 (16 sb iters)
//   b in [256,784): P~ = exp((Q@K^T)/32) causal 128x128 tiles, fp8 sb, 8
//     iters; compact tri grid t = bm(bm+1)/2 + bn (528 tiles); per-row
//     partial sums; diagonal tiles (bn==bm) zero dead slots [bm+1,32).
__global__ __launch_bounds__(256, 4) void k_sv(const bf16_t* __restrict__ xb,
                                               const bf16_t* __restrict__ wvb,
                                               const u8* __restrict__ qk,
                                               bf16_t* __restrict__ vt,
                                               bf16_t* __restrict__ P,
                                               float* __restrict__ rowsum_part) {
    __shared__ __attribute__((aligned(16))) char smem[33792];
    int b = blockIdx.x;
    if (b < 256) {
        int bm = b & 7, bn = b >> 3;  // bn 0..31
        gemm_tile_bf16_sb(wvb + (size_t)bm * 128 * 1024, 1024,
                          xb + (size_t)bn * 128 * 1024, 1024,
                          vt + (size_t)bm * 128 * 4096 + bn * 128, 4096,
                          16, smem);
        return;
    }
    int t = b - 256;  // 0..527
    int bm = (int)((sqrtf(8.f * (float)t + 1.f) - 1.f) * 0.5f);
    while (bm * (bm + 1) / 2 > t) --bm;
    while ((bm + 1) * (bm + 2) / 2 <= t) ++bm;
    int bn = t - bm * (bm + 1) / 2;  // 0..bm
    scores_tile_fp8_sb(qk + (size_t)bm * 128 * 2048, 2048,
                       qk + 1024 + (size_t)bn * 128 * 2048, 2048,
                       P + (size_t)bm * 128 * 4096 + bn * 128, 4096,
                       0.03125f, smem,
                       rowsum_part + (size_t)bm * 128 * 32 + bn,
                       bm * 128, bn * 128);
    if (bn == bm) {  // zero dead rowsum slots for this row block
        float* rp = rowsum_part + (size_t)bm * 128 * 32;
        int tid = threadIdx.x;
        for (int r = tid >> 4; r < 128; r += 16)
            for (int u = bm + 1 + (tid & 15); u < 32; u += 16)
                rp[r * 32 + u] = 0.f;
    }
}

// O = (P~ @ V) * diag(1/rowsum), bf16, BK=64: nk = 2(bm+1) iters.
// Split-K chunk <=22: ns = 1 (bm 0..10) / 2 (bm 11..21) / 3 (bm 22..31).
// Groups: 11 + 22 + 30 = 63; x 8 bn = 504 blocks = ONE generation at 2/CU.
// Single-split computes 1/rowsum into LDS and stores direct; multi-split
// writes fp32 partials (16B coalesced via bounce) for k_reduce.
__global__ __launch_bounds__(256) void k_pv(const bf16_t* __restrict__ P,
                                            const bf16_t* __restrict__ vt,
                                            const float* __restrict__ rowsum_part,
                                            float* __restrict__ out,
                                            float* __restrict__ partials) {
    __shared__ __attribute__((aligned(16))) char smem[65536];
    __shared__ float sInv[128];
    int b = blockIdx.x;
    int bn = b & 7, g = b >> 3;  // g 0..62
    int bm, s, ns;
    if (g < 11)      { bm = g;                  s = 0;             ns = 1; }
    else if (g < 33) { bm = 11 + (g - 11) / 2;  s = (g - 11) % 2;  ns = 2; }
    else             { bm = 22 + (g - 33) / 3;  s = (g - 33) % 3;  ns = 3; }
    int nk = 2 * (bm + 1);
    int kb0 = s * nk / ns;
    int kb1 = (s + 1) * nk / ns;

    const bf16_t* A = P + (size_t)bm * 128 * 4096;
    const bf16_t* B = vt + (size_t)bn * 128 * 4096;
    if (ns == 1) {
        int tid = threadIdx.x;
        if (tid < 128)
            sInv[tid] = 1.f / sum32(rowsum_part + (size_t)(bm * 128 + tid) * 32);
        // visibility of sInv covered by the K-loop's first barrier
        gemm_tile_bf16<2, float>(A, 4096, B, 4096,
                                 out + (size_t)bm * 128 * 1024 + bn * 128, 1024,
                                 kb0, kb1, 1.f, smem, sInv);
    } else {
        int cum = (bm < 22) ? (bm - 11) * 2 : 22 + (bm - 22) * 3;
        gemm_tile_bf16<0, float>(A, 4096, B, 4096,
                                 partials + ((size_t)(cum + s) * 8 + bn) * 16384, 128,
                                 kb0, kb1, 1.f, smem, nullptr);
    }
}

// out tiles for bm in [11,31]: sum 2..3 fp32 partials, scale by 1/rowsum.
// 21 bm x 8 bn = 168 tiles; x16 sub-blocks (8 rows x 128 cols, float4/thr)
// = 2688 blocks.
__global__ __launch_bounds__(256) void k_reduce(const float* __restrict__ partials,
                                                const float* __restrict__ rowsum_part,
                                                float* __restrict__ out) {
    int b = blockIdx.x;
    int t = b % 168, p = b / 168;
    int bm = 11 + t % 21, bn = t / 21;
    int ns = (bm < 22) ? 2 : 3;
    int cum = (bm < 22) ? (bm - 11) * 2 : 22 + (bm - 22) * 3;
    __shared__ float sInv[8];
    int tid = threadIdx.x;
    if (tid < 8) {
        int row = bm * 128 + p * 8 + tid;
        sInv[tid] = 1.f / sum32(rowsum_part + (size_t)row * 32);
    }
    __syncthreads();

    int idx = p * 1024 + tid * 4;
    int lr = idx >> 7, lc = idx & 127;
    float sx = 0.f, sy = 0.f, sz = 0.f, sw = 0.f;
    for (int u = 0; u < ns; ++u) {
        const float4 v = *(const float4*)(partials + ((size_t)(cum + u) * 8 + bn) * 16384 + idx);
        sx += v.x; sy += v.y; sz += v.z; sw += v.w;
    }
    float inv = sInv[lr - p * 8];
    float4 o = {sx * inv, sy * inv, sz * inv, sw * inv};
    *(float4*)(out + (size_t)(bm * 128 + lr) * 1024 + bn * 128 + lc) = o;
}

// fp32 -> bf16 casts: x -> x_bf, Wq|Wk -> Wqk (concat), Wv -> Wv_bf.
__global__ __launch_bounds__(256) void cast_to_bf16(const float* __restrict__ x,
                                                    const float* __restrict__ Wq,
                                                    const float* __restrict__ Wk,
                                                    const float* __restrict__ Wv,
                                                    bf16_t* __restrict__ xb,
                                                    bf16_t* __restrict__ wqk,
                                                    bf16_t* __restrict__ wv) {
    const int NX = (4096 * 1024) / 4;
    const int NW = (1024 * 1024) / 4;
    int idx = blockIdx.x * 256 + threadIdx.x;
    const float* src;
    bf16_t* dst;
    int off;
    if (idx < NX) {
        src = x; dst = xb; off = idx;
    } else if (idx < NX + NW) {
        src = Wq; dst = wqk; off = idx - NX;
    } else if (idx < NX + 2 * NW) {
        src = Wk; dst = wqk + (size_t)NW * 4; off = idx - NX - NW;
    } else {
        src = Wv; dst = wv; off = idx - NX - 2 * NW;
    }
    float4 f = ((const float4*)src)[off];
    bf16x4v o;
    o.x = (bf16_t)f.x; o.y = (bf16_t)f.y; o.z = (bf16_t)f.z; o.w = (bf16_t)f.w;
    *(bf16x4v*)(dst + (size_t)off * 4) = o;
}

extern "C" void kernel_launch(void* const* d_in, const int* in_sizes, int n_in,
                              void* d_out, int out_size, void* d_ws, size_t ws_size,
                              hipStream_t stream) {
    (void)in_sizes; (void)n_in; (void)out_size; (void)ws_size;
    const float* x  = (const float*)d_in[0];
    const float* Wq = (const float*)d_in[1];
    const float* Wk = (const float*)d_in[2];
    const float* Wv = (const float*)d_in[3];
    float* out = (float*)d_out;

    char* ws = (char*)d_ws;
    bf16_t* xb   = (bf16_t*)(ws + (size_t)0);
    bf16_t* wqk  = (bf16_t*)(ws + ((size_t)8 << 20));
    bf16_t* wvb  = (bf16_t*)(ws + ((size_t)12 << 20));
    u8*     qk   = (u8*)(ws + ((size_t)14 << 20));
    bf16_t* vt   = (bf16_t*)(ws + ((size_t)22 << 20));
    bf16_t* P    = (bf16_t*)(ws + ((size_t)30 << 20));
    float* rowsp = (float*)(ws + ((size_t)62 << 20));
    float* parts = (float*)(ws + ((size_t)64 << 20));

    cast_to_bf16<<<7168, 256, 0, stream>>>(x, Wq, Wk, Wv, xb, wqk, wvb);

    // QK (fp8) = x@[Wq;Wk]^T (512 blocks, 2/CU, 1 generation)
    k_qkv<<<512, 256, 0, stream>>>(xb, wqk, qk);

    // Vt (bf16) = Wv@x^T + P~ = exp((Q@K^T)/32) causal (784 blocks, 4/CU)
    k_sv<<<784, 256, 0, stream>>>(xb, wvb, qk, vt, P, rowsp);

    // out = (P~ @ V) * diag(1/rowsum): split-K chunk <=22 (504 blocks, 1 gen)
    k_pv<<<504, 256, 0, stream>>>(P, vt, rowsp, out, parts);
    k_reduce<<<2688, 256, 0, stream>>>(parts, rowsp, out);
}